// Round 5
// baseline (192.442 us; speedup 1.0000x reference)
//
#include <hip/hip_runtime.h>

typedef unsigned short ushort_t;
typedef unsigned char uchar_t;
typedef __attribute__((ext_vector_type(8))) short bf16x8;
typedef __attribute__((ext_vector_type(4))) float f32x4;
typedef __attribute__((ext_vector_type(16))) float f32x16;
typedef __attribute__((ext_vector_type(8))) int v8i;

__device__ __forceinline__ unsigned short f2bf(float f) {
  union { float f; unsigned int u; } v; v.f = f;
  unsigned int r = v.u + 0x7FFFu + ((v.u >> 16) & 1u);
  return (unsigned short)(r >> 16);
}

__device__ __forceinline__ float bf2f(unsigned short u) {
  union { unsigned int i; float f; } v; v.i = ((unsigned int)u) << 16;
  return v.f;
}

__device__ __forceinline__ void gl_lds16(const void* gsrc, void* ldst) {
  __builtin_amdgcn_global_load_lds(
      (const __attribute__((address_space(1))) void*)gsrc,
      (__attribute__((address_space(3))) void*)ldst, 16, 0, 0);
}

__device__ __forceinline__ int frag_idx(int oc, int ci) {
  return (((oc>>4)*8 + (ci>>5))<<9) + ((((ci>>3)&3)*16 + (oc&15))<<3) + (ci&7);
}

// ---------------------------------------------------------------------------
// K1: fragment-major bf16 weight bank Wf[640][256] (Q=wq, K=wk, V=w128@wv)
//     + bias_all[640].  Blocks 0..511: copy/cast QK.  512..639: V-fold, 1 oc
//     per block.
// ---------------------------------------------------------------------------
__global__ __launch_bounds__(256) void k1_weights(
    const float* __restrict__ wq, const float* __restrict__ bq,
    const float* __restrict__ wk, const float* __restrict__ bk,
    const float* __restrict__ wv, const float* __restrict__ bv,
    const float* __restrict__ w128,
    ushort_t* __restrict__ Wf, float* __restrict__ bias_all)
{
  const int ci = threadIdx.x;
  const int oc = blockIdx.x;
  if (oc < 512) {
    const float v = (oc < 256) ? wq[oc*256 + ci] : wk[(oc-256)*256 + ci];
    Wf[frag_idx(oc, ci)] = f2bf(v);
    if (ci == 0) bias_all[oc] = (oc < 256) ? bq[oc] : bk[oc-256];
  } else {
    const int o = oc - 512;
    const float* wr = w128 + (size_t)o*256;
    float a = 0.f;
    for (int co = 0; co < 256; co++) a += wr[co] * wv[co*256 + ci];
    Wf[frag_idx(oc, ci)] = f2bf(a);
    if (ci == 0) {
      float s = 0.f;
      for (int co = 0; co < 256; co++) s += wr[co] * bv[co];
      bias_all[oc] = s;
    }
  }
}

// ---------------------------------------------------------------------------
// K2: MFMA feature GEMM (bf16 16x16x32 internally). Grid (256, 2):
//   x = 64-px tile, y splits the output dim: y=0 -> ot 0..4, y=1 -> ot 5..9.
//   ot 0..3 -> Qf8, 4..7 -> Kf8 (fp8 e4m3 chunks, 1 KB each, 16B/lane),
//   ot 8..9 -> V fp32 [src*8+b][oc][hw]
//   R4: vmcnt(8) -> vmcnt(32): waits exactly the previous ot's 32 loads
//   (oldest-first), keeping the just-issued next-ot prefetch in flight.
// ---------------------------------------------------------------------------
__global__ __launch_bounds__(256) void k2_features(
    const float* __restrict__ x4, const float* __restrict__ x3,
    const ushort_t* __restrict__ Wf, const float* __restrict__ bias_all,
    uchar_t* __restrict__ Qf8, uchar_t* __restrict__ Kf8, float* __restrict__ V)
{
  __shared__ ushort_t Af[32*512];      // 32 KB
  __shared__ ushort_t Wl[2][32*512];   // 2 x 32 KB
  __shared__ ushort_t Lt[64*72];       // repack buffer (bf16)

  const int tid = threadIdx.x;
  const int w = tid >> 6, lane = tid & 63;
  const int mrow = lane & 15, quad = lane >> 4;
  const int ln31 = lane & 31, half = lane >> 5;

  const int px0 = blockIdx.x * 64;
  const int src = px0 >> 13, b = (px0 >> 10) & 7, hw0 = px0 & 1023;
  const float* xp = (src ? x3 : x4) + (size_t)b*262144;

  const int ot0 = blockIdx.y * 5;      // y=0: ot 0..4, y=1: ot 5..9

  for (int kb = 0; kb < 8; kb++)
    gl_lds16(Wf + ((size_t)((ot0*4 + w)*8 + kb)<<9) + lane*8,
             &Wl[ot0&1][(w*8+kb)*512]);

  {
    const int hw = hw0 + w*16 + mrow;
    for (int kb = 0; kb < 8; kb++) {
      const int ch0 = kb*32 + quad*8;
      bf16x8 pk;
      #pragma unroll
      for (int j = 0; j < 8; j++)
        ((ushort_t*)&pk)[j] = f2bf(xp[(size_t)(ch0 + j)*1024 + hw]);
      *(bf16x8*)&Af[(w*8 + kb)*512 + lane*8] = pk;
    }
  }
  __syncthreads();

  for (int ot = ot0; ot < ot0 + 5; ot++) {
    const int nbuf = (ot+1) & 1, cbuf = ot & 1;
    if (ot + 1 < ot0 + 5) {
      for (int kb = 0; kb < 8; kb++)
        gl_lds16(Wf + ((size_t)(((ot+1)*4 + w)*8 + kb)<<9) + lane*8,
                 &Wl[nbuf][(w*8+kb)*512]);
      asm volatile("s_waitcnt vmcnt(32)" ::: "memory");
    } else {
      asm volatile("s_waitcnt vmcnt(0)" ::: "memory");
    }

    f32x4 acc[4];
    #pragma unroll
    for (int lg = 0; lg < 4; lg++) acc[lg] = (f32x4){0.f,0.f,0.f,0.f};
    #pragma unroll
    for (int kb = 0; kb < 8; kb++) {
      const bf16x8 a = *(const bf16x8*)&Wl[cbuf][(w*8 + kb)*512 + lane*8];
      #pragma unroll
      for (int lg = 0; lg < 4; lg++) {
        const bf16x8 bx = *(const bf16x8*)&Af[(lg*8 + kb)*512 + lane*8];
        acc[lg] = __builtin_amdgcn_mfma_f32_16x16x32_bf16(a, bx, acc[lg], 0, 0, 0);
      }
    }
    const int ocl = w*16 + quad*4;
    const float4 bias4 = *(const float4*)&bias_all[ot*64 + ocl];

    if (ot < 8) {
      __syncthreads();
      #pragma unroll
      for (int lg = 0; lg < 4; lg++) {
        const int px = lg*16 + mrow;
        ushort4 pk;
        pk.x = f2bf(acc[lg][0] + bias4.x);
        pk.y = f2bf(acc[lg][1] + bias4.y);
        pk.z = f2bf(acc[lg][2] + bias4.z);
        pk.w = f2bf(acc[lg][3] + bias4.w);
        *(ushort4*)&Lt[px*72 + ocl] = pk;
      }
      __syncthreads();
      // emit one fp8 chunk per wave: wave w -> g = w>>1, e = w&1
      const int g = w >> 1, e = w & 1;
      const int row = g*32 + ln31;
      const ushort_t* lp = &Lt[row*72 + e*32 + half*8];
      float fl[8], fh[8];
      #pragma unroll
      for (int j = 0; j < 8; j++) { fl[j] = bf2f(lp[j]); fh[j] = bf2f(lp[16+j]); }
      int w0 = __builtin_amdgcn_cvt_pk_fp8_f32(fl[0], fl[1], 0, 0);
      w0     = __builtin_amdgcn_cvt_pk_fp8_f32(fl[2], fl[3], w0, 1);
      int w1 = __builtin_amdgcn_cvt_pk_fp8_f32(fl[4], fl[5], 0, 0);
      w1     = __builtin_amdgcn_cvt_pk_fp8_f32(fl[6], fl[7], w1, 1);
      int w2 = __builtin_amdgcn_cvt_pk_fp8_f32(fh[0], fh[1], 0, 0);
      w2     = __builtin_amdgcn_cvt_pk_fp8_f32(fh[2], fh[3], w2, 1);
      int w3 = __builtin_amdgcn_cvt_pk_fp8_f32(fh[4], fh[5], 0, 0);
      w3     = __builtin_amdgcn_cvt_pk_fp8_f32(fh[6], fh[7], w3, 1);
      uchar_t* dst = (ot < 4) ? Qf8 : Kf8;
      const size_t chunk = (size_t)((px0>>5) + g)*8 + (ot&3)*2 + e;
      int4 pk4; pk4.x = w0; pk4.y = w1; pk4.z = w2; pk4.w = w3;
      *(int4*)(dst + (chunk<<10) + lane*16) = pk4;
    } else {
      const int ocv0 = (ot-8)*64 + ocl;
      float* vb = V + (((size_t)(src*8 + b)*128) << 10) + hw0;
      #pragma unroll
      for (int lg = 0; lg < 4; lg++) {
        vb[(size_t)(ocv0+0)*1024 + lg*16 + mrow] = acc[lg][0] + bias4.x;
        vb[(size_t)(ocv0+1)*1024 + lg*16 + mrow] = acc[lg][1] + bias4.y;
        vb[(size_t)(ocv0+2)*1024 + lg*16 + mrow] = acc[lg][2] + bias4.z;
        vb[(size_t)(ocv0+3)*1024 + lg*16 + mrow] = acc[lg][3] + bias4.w;
      }
    }
  }
}

// ---------------------------------------------------------------------------
// K3: MX-scaled fp8 MFMA 32x32x64 (unit scales = plain fp8 at 2x rate).
//   Block = 512 rows x one key-batch (1024 cols), 8 waves x 64 rows (2 rg32),
//   2 waves/SIMD.
//   R5: B fragments read DIRECTLY from global (L2-resident Kf8, 4 MB) into
//   registers.  R3/R4 analysis: with LDS staging the CU-shared LDS read port
//   ran at ~75% (1 ds_read_b128 ~12cy per 16.1cy MFMA window) with barrier-
//   lockstep bursts -> lgkmcnt queuing capped MfmaUtil at ~42%.  Direct L2
//   streaming: 1 GB total / 34.5 TB/s ~= 30us, overlapping the 27.5us MFMA
//   floor; NO LDS, NO barriers -- the two waves/SIMD free-run in ping-pong
//   (one wave's 515cy MFMA burst covers the other's ~300cy L2 latency).
//   Stage loop rolled (R3: unroll -> spill); no manual reg pipeline (R4).
//   Pm layout: [batch(16)][row(16384)].  Grid 512 x 512 threads.
// ---------------------------------------------------------------------------
__global__ __launch_bounds__(512, 2) void k3_smax(
    const uchar_t* __restrict__ Qf8, const uchar_t* __restrict__ Kf8,
    float* __restrict__ Pm)
{
  const int tid = threadIdx.x;
  const int bt = blockIdx.x >> 5;      // key-batch 0..15
  const int rt = blockIdx.x & 31;      // row-tile (512 rows)
  const int w = tid >> 6, lane = tid & 63;   // w: 0..7
  const int ln31 = lane & 31, half = lane >> 5;

  const int rgb = rt*16 + w*2;         // wave's first row-grp32 (owns 2)

  // Q fragments: 2 rg x 4 u-windows, v8i each (64 VGPR), resident whole kernel
  v8i qa[2][4];
  #pragma unroll
  for (int rg = 0; rg < 2; rg++)
    #pragma unroll
    for (int u = 0; u < 4; u++) {
      const int4 p0 = *(const int4*)(Qf8 + (((size_t)(rgb + rg)*8 + 2*u+0)<<10) + lane*16);
      const int4 p1 = *(const int4*)(Qf8 + (((size_t)(rgb + rg)*8 + 2*u+1)<<10) + lane*16);
      qa[rg][u] = (v8i){p0.x, p0.y, p0.z, p0.w, p1.x, p1.y, p1.z, p1.w};
    }

  f32x16 zv;
  #pragma unroll
  for (int i = 0; i < 16; i++) zv[i] = 0.f;
  f32x16 rmax[2];
  #pragma unroll
  for (int rg = 0; rg < 2; rg++)
    #pragma unroll
    for (int i = 0; i < 16; i++) rmax[rg][i] = -3.4e38f;

  // bt's key column: 32 col-groups x 8 fragments x 1 KB = 256 KB (L2-hot)
  const uchar_t* kbase = Kf8 + ((size_t)(bt*32*8) << 10) + lane*16;

  #pragma unroll 1                      // keep rolled (R3: unroll -> spill)
  for (int cg = 0; cg < 32; cg++) {
    const uchar_t* kc = kbase + ((size_t)(cg*8) << 10);
    f32x16 a0 = zv, a1 = zv;           // two chains: rg=0, rg=1
    #pragma unroll
    for (int u = 0; u < 4; u++) {
      const int4 b0 = *(const int4*)(kc + (2*u+0)*1024);
      const int4 b1 = *(const int4*)(kc + (2*u+1)*1024);
      const v8i bu = (v8i){b0.x, b0.y, b0.z, b0.w, b1.x, b1.y, b1.z, b1.w};
      a0 = __builtin_amdgcn_mfma_scale_f32_32x32x64_f8f6f4(
          qa[0][u], bu, a0, 0, 0, 0, 0x7F7F7F7F, 0, 0x7F7F7F7F);
      a1 = __builtin_amdgcn_mfma_scale_f32_32x32x64_f8f6f4(
          qa[1][u], bu, a1, 0, 0, 0, 0x7F7F7F7F, 0, 0x7F7F7F7F);
    }
    #pragma unroll
    for (int i = 0; i < 16; i++) {
      rmax[0][i] = fmaxf(rmax[0][i], a0[i]);
      rmax[1][i] = fmaxf(rmax[1][i], a1[i]);
    }
  }

  // epilogue: per-row max over 32 cols (5 xor-shuffles in each 32-lane half)
  // C/D: col = lane&31, row = (reg&3) + 8*(reg>>2) + 4*half (shape-determined)
  #pragma unroll
  for (int rg = 0; rg < 2; rg++) {
    #pragma unroll
    for (int e = 0; e < 16; e++) {
      float v = rmax[rg][e];
      v = fmaxf(v, __shfl_xor(v, 1));
      v = fmaxf(v, __shfl_xor(v, 2));
      v = fmaxf(v, __shfl_xor(v, 4));
      v = fmaxf(v, __shfl_xor(v, 8));
      v = fmaxf(v, __shfl_xor(v, 16));
      if (ln31 == 0) {
        const int row = rt*512 + w*64 + rg*32 + (e&3) + 8*(e>>2) + 4*half;
        Pm[(size_t)bt*16384 + row] = v;
      }
    }
  }
}

// ---------------------------------------------------------------------------
// K5: fused gates + output.  Block = one (b, ch) pair, 256 threads x 4 hw.
//   Recomputes its gate row's softmax from Pm (deterministic, identical across
//   blocks sharing the row): logits = mean over 8 batch-maxes * scale.
//   out[b][ch][hw] = softmax_hw(logit) * V + b128.  ch: [x34|a_x4|x43|b_x3]
// ---------------------------------------------------------------------------
__global__ __launch_bounds__(256) void k5_out(
    const float* __restrict__ V, const float* __restrict__ Pm,
    const float* __restrict__ b128, float* __restrict__ out)
{
  __shared__ float xw[2][4];
  const int tid = threadIdx.x;
  const int ch = blockIdx.x & 511, b = blockIdx.x >> 9;
  const int blk = ch >> 7, o = ch & 127;
  const int gidx = (blk == 0) ? 2 : (blk == 1) ? 0 : (blk == 2) ? 1 : 3;
  const int src = (blk >= 2) ? 1 : 0;
  const int qset = gidx >> 1, side = gidx & 1;

  // logits for hw = tid*4 .. tid*4+3 (coalesced float4 per batch)
  const float4* Pm4 = (const float4*)(Pm + (size_t)side*8*16384 + qset*8192 + b*1024);
  float4 l = {0.f, 0.f, 0.f, 0.f};
  #pragma unroll
  for (int t = 0; t < 8; t++) {
    const float4 p = Pm4[t*4096 + tid];
    l.x += p.x; l.y += p.y; l.z += p.z; l.w += p.w;
  }
  const float sc = 0.125f * 0.0625f;   // mean over 8 batches * 1/sqrt(256)
  l.x *= sc; l.y *= sc; l.z *= sc; l.w *= sc;

  const int w = tid >> 6, lane = tid & 63;
  float m = fmaxf(fmaxf(l.x, l.y), fmaxf(l.z, l.w));
  #pragma unroll
  for (int d = 1; d < 64; d <<= 1) m = fmaxf(m, __shfl_xor(m, d));
  if (lane == 0) xw[0][w] = m;
  __syncthreads();
  m = fmaxf(fmaxf(xw[0][0], xw[0][1]), fmaxf(xw[0][2], xw[0][3]));

  float4 e;
  e.x = expf(l.x - m); e.y = expf(l.y - m);
  e.z = expf(l.z - m); e.w = expf(l.w - m);
  float s = e.x + e.y + e.z + e.w;
  #pragma unroll
  for (int d = 1; d < 64; d <<= 1) s += __shfl_xor(s, d);
  if (lane == 0) xw[1][w] = s;
  __syncthreads();
  s = xw[1][0] + xw[1][1] + xw[1][2] + xw[1][3];
  const float inv = 1.f / s;

  const int hw0 = tid << 2;
  const float4 v = *(const float4*)&V[((size_t)((src*8 + b)*128 + o) << 10) + hw0];
  const float bias = b128[o];
  float4 r;
  r.x = e.x*inv*v.x + bias; r.y = e.y*inv*v.y + bias;
  r.z = e.z*inv*v.z + bias; r.w = e.w*inv*v.w + bias;
  *(float4*)&out[((size_t)(b*512 + ch) << 10) + hw0] = r;
}

// ---------------------------------------------------------------------------
extern "C" void kernel_launch(void* const* d_in, const int* in_sizes, int n_in,
                              void* d_out, int out_size, void* d_ws, size_t ws_size,
                              hipStream_t stream)
{
  const float* x4   = (const float*)d_in[0];
  const float* x3   = (const float*)d_in[1];
  const float* wq   = (const float*)d_in[2];
  const float* bq   = (const float*)d_in[3];
  const float* wk   = (const float*)d_in[4];
  const float* bk   = (const float*)d_in[5];
  const float* wv   = (const float*)d_in[6];
  const float* bv   = (const float*)d_in[7];
  const float* w128 = (const float*)d_in[8];
  const float* b128 = (const float*)d_in[9];
  float* out = (float*)d_out;

  char* ws = (char*)d_ws;
  uchar_t*  Qf8 = (uchar_t*)ws;  ws += (size_t)512*8*1024;      // 4 MB
  uchar_t*  Kf8 = (uchar_t*)ws;  ws += (size_t)512*8*1024;      // 4 MB
  float*    V   = (float*)ws;    ws += (size_t)2*8*128*1024*4;  // 8 MB
  float*    Pm  = (float*)ws;    ws += (size_t)16*16384*4;      // 1 MB
  ushort_t* Wf  = (ushort_t*)ws; ws += (size_t)640*256*2;       // 320 KB
  float* bias_all = (float*)ws;                                 // 2.5 KB

  k1_weights <<<640,          256, 0, stream>>>(wq, bq, wk, bk, wv, bv, w128, Wf, bias_all);
  k2_features<<<dim3(256, 2), 256, 0, stream>>>(x4, x3, Wf, bias_all, Qf8, Kf8, V);
  k3_smax    <<<512,          512, 0, stream>>>(Qf8, Kf8, Pm);
  k5_out     <<<4096,         256, 0, stream>>>(V, Pm, b128, out);
}

// Round 6
// 184.644 us; speedup vs baseline: 1.0422x; 1.0422x over previous
//
#include <hip/hip_runtime.h>

typedef unsigned short ushort_t;
typedef unsigned char uchar_t;
typedef __attribute__((ext_vector_type(8))) short bf16x8;
typedef __attribute__((ext_vector_type(4))) float f32x4;
typedef __attribute__((ext_vector_type(16))) float f32x16;
typedef __attribute__((ext_vector_type(8))) int v8i;

__device__ __forceinline__ unsigned short f2bf(float f) {
  union { float f; unsigned int u; } v; v.f = f;
  unsigned int r = v.u + 0x7FFFu + ((v.u >> 16) & 1u);
  return (unsigned short)(r >> 16);
}

__device__ __forceinline__ float bf2f(unsigned short u) {
  union { unsigned int i; float f; } v; v.i = ((unsigned int)u) << 16;
  return v.f;
}

__device__ __forceinline__ void gl_lds16(const void* gsrc, void* ldst) {
  __builtin_amdgcn_global_load_lds(
      (const __attribute__((address_space(1))) void*)gsrc,
      (__attribute__((address_space(3))) void*)ldst, 16, 0, 0);
}

__device__ __forceinline__ int frag_idx(int oc, int ci) {
  return (((oc>>4)*8 + (ci>>5))<<9) + ((((ci>>3)&3)*16 + (oc&15))<<3) + (ci&7);
}

// ---------------------------------------------------------------------------
// K1: fragment-major bf16 weight bank Wf[640][256] (Q=wq, K=wk, V=w128@wv)
//     + bias_all[640].  Blocks 0..511: copy/cast QK.  512..639: V-fold, 1 oc
//     per block.
// ---------------------------------------------------------------------------
__global__ __launch_bounds__(256) void k1_weights(
    const float* __restrict__ wq, const float* __restrict__ bq,
    const float* __restrict__ wk, const float* __restrict__ bk,
    const float* __restrict__ wv, const float* __restrict__ bv,
    const float* __restrict__ w128,
    ushort_t* __restrict__ Wf, float* __restrict__ bias_all)
{
  const int ci = threadIdx.x;
  const int oc = blockIdx.x;
  if (oc < 512) {
    const float v = (oc < 256) ? wq[oc*256 + ci] : wk[(oc-256)*256 + ci];
    Wf[frag_idx(oc, ci)] = f2bf(v);
    if (ci == 0) bias_all[oc] = (oc < 256) ? bq[oc] : bk[oc-256];
  } else {
    const int o = oc - 512;
    const float* wr = w128 + (size_t)o*256;
    float a = 0.f;
    for (int co = 0; co < 256; co++) a += wr[co] * wv[co*256 + ci];
    Wf[frag_idx(oc, ci)] = f2bf(a);
    if (ci == 0) {
      float s = 0.f;
      for (int co = 0; co < 256; co++) s += wr[co] * bv[co];
      bias_all[oc] = s;
    }
  }
}

// ---------------------------------------------------------------------------
// K2: MFMA feature GEMM (bf16 16x16x32 internally). Grid (256, 2):
//   x = 64-px tile, y splits the output dim: y=0 -> ot 0..4, y=1 -> ot 5..9.
//   ot 0..3 -> Qf8, 4..7 -> Kf8 (fp8 e4m3 chunks, 1 KB each, 16B/lane),
//   ot 8..9 -> V fp32 [src*8+b][oc][hw]
//   R4: vmcnt(8) -> vmcnt(32): waits exactly the previous ot's 32 loads
//   (oldest-first), keeping the just-issued next-ot prefetch in flight.
// ---------------------------------------------------------------------------
__global__ __launch_bounds__(256) void k2_features(
    const float* __restrict__ x4, const float* __restrict__ x3,
    const ushort_t* __restrict__ Wf, const float* __restrict__ bias_all,
    uchar_t* __restrict__ Qf8, uchar_t* __restrict__ Kf8, float* __restrict__ V)
{
  __shared__ ushort_t Af[32*512];      // 32 KB
  __shared__ ushort_t Wl[2][32*512];   // 2 x 32 KB
  __shared__ ushort_t Lt[64*72];       // repack buffer (bf16)

  const int tid = threadIdx.x;
  const int w = tid >> 6, lane = tid & 63;
  const int mrow = lane & 15, quad = lane >> 4;
  const int ln31 = lane & 31, half = lane >> 5;

  const int px0 = blockIdx.x * 64;
  const int src = px0 >> 13, b = (px0 >> 10) & 7, hw0 = px0 & 1023;
  const float* xp = (src ? x3 : x4) + (size_t)b*262144;

  const int ot0 = blockIdx.y * 5;      // y=0: ot 0..4, y=1: ot 5..9

  for (int kb = 0; kb < 8; kb++)
    gl_lds16(Wf + ((size_t)((ot0*4 + w)*8 + kb)<<9) + lane*8,
             &Wl[ot0&1][(w*8+kb)*512]);

  {
    const int hw = hw0 + w*16 + mrow;
    for (int kb = 0; kb < 8; kb++) {
      const int ch0 = kb*32 + quad*8;
      bf16x8 pk;
      #pragma unroll
      for (int j = 0; j < 8; j++)
        ((ushort_t*)&pk)[j] = f2bf(xp[(size_t)(ch0 + j)*1024 + hw]);
      *(bf16x8*)&Af[(w*8 + kb)*512 + lane*8] = pk;
    }
  }
  __syncthreads();

  for (int ot = ot0; ot < ot0 + 5; ot++) {
    const int nbuf = (ot+1) & 1, cbuf = ot & 1;
    if (ot + 1 < ot0 + 5) {
      for (int kb = 0; kb < 8; kb++)
        gl_lds16(Wf + ((size_t)(((ot+1)*4 + w)*8 + kb)<<9) + lane*8,
                 &Wl[nbuf][(w*8+kb)*512]);
      asm volatile("s_waitcnt vmcnt(32)" ::: "memory");
    } else {
      asm volatile("s_waitcnt vmcnt(0)" ::: "memory");
    }

    f32x4 acc[4];
    #pragma unroll
    for (int lg = 0; lg < 4; lg++) acc[lg] = (f32x4){0.f,0.f,0.f,0.f};
    #pragma unroll
    for (int kb = 0; kb < 8; kb++) {
      const bf16x8 a = *(const bf16x8*)&Wl[cbuf][(w*8 + kb)*512 + lane*8];
      #pragma unroll
      for (int lg = 0; lg < 4; lg++) {
        const bf16x8 bx = *(const bf16x8*)&Af[(lg*8 + kb)*512 + lane*8];
        acc[lg] = __builtin_amdgcn_mfma_f32_16x16x32_bf16(a, bx, acc[lg], 0, 0, 0);
      }
    }
    const int ocl = w*16 + quad*4;
    const float4 bias4 = *(const float4*)&bias_all[ot*64 + ocl];

    if (ot < 8) {
      __syncthreads();
      #pragma unroll
      for (int lg = 0; lg < 4; lg++) {
        const int px = lg*16 + mrow;
        ushort4 pk;
        pk.x = f2bf(acc[lg][0] + bias4.x);
        pk.y = f2bf(acc[lg][1] + bias4.y);
        pk.z = f2bf(acc[lg][2] + bias4.z);
        pk.w = f2bf(acc[lg][3] + bias4.w);
        *(ushort4*)&Lt[px*72 + ocl] = pk;
      }
      __syncthreads();
      // emit one fp8 chunk per wave: wave w -> g = w>>1, e = w&1
      const int g = w >> 1, e = w & 1;
      const int row = g*32 + ln31;
      const ushort_t* lp = &Lt[row*72 + e*32 + half*8];
      float fl[8], fh[8];
      #pragma unroll
      for (int j = 0; j < 8; j++) { fl[j] = bf2f(lp[j]); fh[j] = bf2f(lp[16+j]); }
      int w0 = __builtin_amdgcn_cvt_pk_fp8_f32(fl[0], fl[1], 0, 0);
      w0     = __builtin_amdgcn_cvt_pk_fp8_f32(fl[2], fl[3], w0, 1);
      int w1 = __builtin_amdgcn_cvt_pk_fp8_f32(fl[4], fl[5], 0, 0);
      w1     = __builtin_amdgcn_cvt_pk_fp8_f32(fl[6], fl[7], w1, 1);
      int w2 = __builtin_amdgcn_cvt_pk_fp8_f32(fh[0], fh[1], 0, 0);
      w2     = __builtin_amdgcn_cvt_pk_fp8_f32(fh[2], fh[3], w2, 1);
      int w3 = __builtin_amdgcn_cvt_pk_fp8_f32(fh[4], fh[5], 0, 0);
      w3     = __builtin_amdgcn_cvt_pk_fp8_f32(fh[6], fh[7], w3, 1);
      uchar_t* dst = (ot < 4) ? Qf8 : Kf8;
      const size_t chunk = (size_t)((px0>>5) + g)*8 + (ot&3)*2 + e;
      int4 pk4; pk4.x = w0; pk4.y = w1; pk4.z = w2; pk4.w = w3;
      *(int4*)(dst + (chunk<<10) + lane*16) = pk4;
    } else {
      const int ocv0 = (ot-8)*64 + ocl;
      float* vb = V + (((size_t)(src*8 + b)*128) << 10) + hw0;
      #pragma unroll
      for (int lg = 0; lg < 4; lg++) {
        vb[(size_t)(ocv0+0)*1024 + lg*16 + mrow] = acc[lg][0] + bias4.x;
        vb[(size_t)(ocv0+1)*1024 + lg*16 + mrow] = acc[lg][1] + bias4.y;
        vb[(size_t)(ocv0+2)*1024 + lg*16 + mrow] = acc[lg][2] + bias4.z;
        vb[(size_t)(ocv0+3)*1024 + lg*16 + mrow] = acc[lg][3] + bias4.w;
      }
    }
  }
}

// ---------------------------------------------------------------------------
// K3: MX-scaled fp8 MFMA 32x32x64 (unit scales = plain fp8 at 2x rate).
//   Block = 512 rows x one key-batch (1024 cols), 8 waves x 64 rows (2 rg32),
//   2 waves/SIMD, LDS double-buffered 2x32KB (R3 layout, 65us baseline).
//   R6: T3+T4 8-phase schedule (m201 template).  R3's stage was 1-phase:
//   all 8 waves in lockstep {read-burst, MFMA-burst, fold} -> port(3072cy) +
//   pipe(4400cy) + VALU(1650cy) ran SERIALLY (stage 9750cy).  Now each stage
//   = 4 phases (1 cgl each): {ds_read 8 frags | ph0: issue next-stage gl_lds
//   | fold prev acc} -> s_barrier -> lgkmcnt(0) -> setprio(1) 8xMFMA
//   setprio(0) -> s_barrier.  Raw s_barrier (NOT __syncthreads) so the
//   stage prefetch is not drained mid-stage; vmcnt(0) only at the stage
//   boundary (gl_lds issued 3 phases earlier -> free).  Fold deferred one
//   phase (fa0/fa1 carry, init -inf = no-op first fold) so it lands in the
//   read window.  Phase k+1's ds_reads issue while phase k's MFMAs drain ->
//   port/pipe overlap.  Stage loop rolled (R3: unroll -> 50MB spill).
//   Liveness ~207 regs: qa 64 + frags 32 + fa 32 + acc 32 + rmax 32 + addr.
//   Pm layout: [batch(16)][row(16384)].  Grid 512 x 512 threads.
// ---------------------------------------------------------------------------
__global__ __launch_bounds__(512, 2) void k3_smax(
    const uchar_t* __restrict__ Qf8, const uchar_t* __restrict__ Kf8,
    float* __restrict__ Pm)
{
  __shared__ __align__(16) uchar_t Kl[2][32768];   // 2 x 32 KB

  const int tid = threadIdx.x;
  const int bt = blockIdx.x >> 5;      // key-batch 0..15
  const int rt = blockIdx.x & 31;      // row-tile (512 rows)
  const int w = tid >> 6, lane = tid & 63;   // w: 0..7
  const int ln31 = lane & 31, half = lane >> 5;

  const int rgb = rt*16 + w*2;         // wave's first row-grp32 (owns 2)
  const int ph = (blockIdx.x & 1)*4;   // stage-phase rotation (max is
                                       // order-invariant, so any cg order ok)

  // prologue: stage s=0: 32 chunks (4 cgl x 8 kp); wave w -> c = w*4..w*4+3
  #pragma unroll
  for (int q = 0; q < 4; q++) {
    const int c = w*4 + q;             // cgl = c>>3, kp = c&7
    const int cg = bt*32 + ph*4 + (c>>3);
    gl_lds16(Kf8 + (((size_t)cg*8 + (c&7))<<10) + lane*16, &Kl[0][c*1024]);
  }

  // Q fragments: 2 rg x 4 u-windows, v8i each (64 VGPR), resident whole kernel
  v8i qa[2][4];
  #pragma unroll
  for (int rg = 0; rg < 2; rg++)
    #pragma unroll
    for (int u = 0; u < 4; u++) {
      const int4 p0 = *(const int4*)(Qf8 + (((size_t)(rgb + rg)*8 + 2*u+0)<<10) + lane*16);
      const int4 p1 = *(const int4*)(Qf8 + (((size_t)(rgb + rg)*8 + 2*u+1)<<10) + lane*16);
      qa[rg][u] = (v8i){p0.x, p0.y, p0.z, p0.w, p1.x, p1.y, p1.z, p1.w};
    }

  f32x16 zv;
  #pragma unroll
  for (int i = 0; i < 16; i++) zv[i] = 0.f;
  f32x16 rmax[2];
  #pragma unroll
  for (int rg = 0; rg < 2; rg++)
    #pragma unroll
    for (int i = 0; i < 16; i++) rmax[rg][i] = -3.4e38f;

  // deferred-fold carry (first fold is a no-op on -inf)
  f32x16 fa0, fa1;
  #pragma unroll
  for (int i = 0; i < 16; i++) { fa0[i] = -3.4e38f; fa1[i] = -3.4e38f; }

  // stage-0 data ready before first phase reads it
  asm volatile("s_waitcnt vmcnt(0)" ::: "memory");
  __builtin_amdgcn_s_barrier();

  #pragma unroll 1                      // KEEP ROLLED (R3: unroll -> spill)
  for (int s = 0; s < 8; s++) {
    const uchar_t* kl = &Kl[s & 1][0];
    #pragma unroll
    for (int c = 0; c < 4; c++) {      // 4 phases per stage, one cgl each
      // --- phase: read this cgl's 8 B-fragments into registers
      int4 fr[8];
      #pragma unroll
      for (int t = 0; t < 8; t++)
        fr[t] = *(const int4*)&kl[(c*8 + t)*1024 + lane*16];
      // --- phase 0: issue next stage's gl_lds (drained at stage boundary)
      if (c == 0 && s < 7) {
        const int sn = (s + 1 + ph) & 7;
        #pragma unroll
        for (int q = 0; q < 4; q++) {
          const int cc = w*4 + q;
          const int cg = bt*32 + sn*4 + (cc>>3);
          gl_lds16(Kf8 + (((size_t)cg*8 + (cc&7))<<10) + lane*16,
                   &Kl[(s+1)&1][cc*1024]);
        }
      }
      // --- deferred fold of previous phase's accumulators (off MFMA path)
      #pragma unroll
      for (int i = 0; i < 16; i++) {
        rmax[0][i] = fmaxf(rmax[0][i], fa0[i]);
        rmax[1][i] = fmaxf(rmax[1][i], fa1[i]);
      }
      // --- barrier #1: reads complete during the sync wait
      __builtin_amdgcn_s_barrier();
      asm volatile("s_waitcnt lgkmcnt(0)" ::: "memory");
      __builtin_amdgcn_sched_barrier(0);
      // --- MFMA cluster
      f32x16 a0 = zv, a1 = zv;
      __builtin_amdgcn_s_setprio(1);
      #pragma unroll
      for (int u = 0; u < 4; u++) {
        const v8i bu = (v8i){fr[2*u].x,   fr[2*u].y,   fr[2*u].z,   fr[2*u].w,
                             fr[2*u+1].x, fr[2*u+1].y, fr[2*u+1].z, fr[2*u+1].w};
        a0 = __builtin_amdgcn_mfma_scale_f32_32x32x64_f8f6f4(
            qa[0][u], bu, a0, 0, 0, 0, 0x7F7F7F7F, 0, 0x7F7F7F7F);
        a1 = __builtin_amdgcn_mfma_scale_f32_32x32x64_f8f6f4(
            qa[1][u], bu, a1, 0, 0, 0, 0x7F7F7F7F, 0, 0x7F7F7F7F);
      }
      __builtin_amdgcn_s_setprio(0);
      fa0 = a0; fa1 = a1;               // rename into the fold carry
      // --- barrier #2 (+ stage-boundary gl_lds drain on last phase)
      if (c == 3)
        asm volatile("s_waitcnt vmcnt(0)" ::: "memory");
      __builtin_amdgcn_s_barrier();
    }
  }
  // final deferred fold
  #pragma unroll
  for (int i = 0; i < 16; i++) {
    rmax[0][i] = fmaxf(rmax[0][i], fa0[i]);
    rmax[1][i] = fmaxf(rmax[1][i], fa1[i]);
  }

  // epilogue: per-row max over 32 cols (5 xor-shuffles in each 32-lane half)
  // C/D: col = lane&31, row = (reg&3) + 8*(reg>>2) + 4*half (shape-determined)
  #pragma unroll
  for (int rg = 0; rg < 2; rg++) {
    #pragma unroll
    for (int e = 0; e < 16; e++) {
      float v = rmax[rg][e];
      v = fmaxf(v, __shfl_xor(v, 1));
      v = fmaxf(v, __shfl_xor(v, 2));
      v = fmaxf(v, __shfl_xor(v, 4));
      v = fmaxf(v, __shfl_xor(v, 8));
      v = fmaxf(v, __shfl_xor(v, 16));
      if (ln31 == 0) {
        const int row = rt*512 + w*64 + rg*32 + (e&3) + 8*(e>>2) + 4*half;
        Pm[(size_t)bt*16384 + row] = v;
      }
    }
  }
}

// ---------------------------------------------------------------------------
// K5: fused gates + output.  Block = one (b, ch) pair, 256 threads x 4 hw.
//   Recomputes its gate row's softmax from Pm (deterministic, identical across
//   blocks sharing the row): logits = mean over 8 batch-maxes * scale.
//   out[b][ch][hw] = softmax_hw(logit) * V + b128.  ch: [x34|a_x4|x43|b_x3]
// ---------------------------------------------------------------------------
__global__ __launch_bounds__(256) void k5_out(
    const float* __restrict__ V, const float* __restrict__ Pm,
    const float* __restrict__ b128, float* __restrict__ out)
{
  __shared__ float xw[2][4];
  const int tid = threadIdx.x;
  const int ch = blockIdx.x & 511, b = blockIdx.x >> 9;
  const int blk = ch >> 7, o = ch & 127;
  const int gidx = (blk == 0) ? 2 : (blk == 1) ? 0 : (blk == 2) ? 1 : 3;
  const int src = (blk >= 2) ? 1 : 0;
  const int qset = gidx >> 1, side = gidx & 1;

  // logits for hw = tid*4 .. tid*4+3 (coalesced float4 per batch)
  const float4* Pm4 = (const float4*)(Pm + (size_t)side*8*16384 + qset*8192 + b*1024);
  float4 l = {0.f, 0.f, 0.f, 0.f};
  #pragma unroll
  for (int t = 0; t < 8; t++) {
    const float4 p = Pm4[t*4096 + tid];
    l.x += p.x; l.y += p.y; l.z += p.z; l.w += p.w;
  }
  const float sc = 0.125f * 0.0625f;   // mean over 8 batches * 1/sqrt(256)
  l.x *= sc; l.y *= sc; l.z *= sc; l.w *= sc;

  const int w = tid >> 6, lane = tid & 63;
  float m = fmaxf(fmaxf(l.x, l.y), fmaxf(l.z, l.w));
  #pragma unroll
  for (int d = 1; d < 64; d <<= 1) m = fmaxf(m, __shfl_xor(m, d));
  if (lane == 0) xw[0][w] = m;
  __syncthreads();
  m = fmaxf(fmaxf(xw[0][0], xw[0][1]), fmaxf(xw[0][2], xw[0][3]));

  float4 e;
  e.x = expf(l.x - m); e.y = expf(l.y - m);
  e.z = expf(l.z - m); e.w = expf(l.w - m);
  float s = e.x + e.y + e.z + e.w;
  #pragma unroll
  for (int d = 1; d < 64; d <<= 1) s += __shfl_xor(s, d);
  if (lane == 0) xw[1][w] = s;
  __syncthreads();
  s = xw[1][0] + xw[1][1] + xw[1][2] + xw[1][3];
  const float inv = 1.f / s;

  const int hw0 = tid << 2;
  const float4 v = *(const float4*)&V[((size_t)((src*8 + b)*128 + o) << 10) + hw0];
  const float bias = b128[o];
  float4 r;
  r.x = e.x*inv*v.x + bias; r.y = e.y*inv*v.y + bias;
  r.z = e.z*inv*v.z + bias; r.w = e.w*inv*v.w + bias;
  *(float4*)&out[((size_t)(b*512 + ch) << 10) + hw0] = r;
}

// ---------------------------------------------------------------------------
extern "C" void kernel_launch(void* const* d_in, const int* in_sizes, int n_in,
                              void* d_out, int out_size, void* d_ws, size_t ws_size,
                              hipStream_t stream)
{
  const float* x4   = (const float*)d_in[0];
  const float* x3   = (const float*)d_in[1];
  const float* wq   = (const float*)d_in[2];
  const float* bq   = (const float*)d_in[3];
  const float* wk   = (const float*)d_in[4];
  const float* bk   = (const float*)d_in[5];
  const float* wv   = (const float*)d_in[6];
  const float* bv   = (const float*)d_in[7];
  const float* w128 = (const float*)d_in[8];
  const float* b128 = (const float*)d_in[9];
  float* out = (float*)d_out;

  char* ws = (char*)d_ws;
  uchar_t*  Qf8 = (uchar_t*)ws;  ws += (size_t)512*8*1024;      // 4 MB
  uchar_t*  Kf8 = (uchar_t*)ws;  ws += (size_t)512*8*1024;      // 4 MB
  float*    V   = (float*)ws;    ws += (size_t)2*8*128*1024*4;  // 8 MB
  float*    Pm  = (float*)ws;    ws += (size_t)16*16384*4;      // 1 MB
  ushort_t* Wf  = (ushort_t*)ws; ws += (size_t)640*256*2;       // 320 KB
  float* bias_all = (float*)ws;                                 // 2.5 KB

  k1_weights <<<640,          256, 0, stream>>>(wq, bq, wk, bk, wv, bv, w128, Wf, bias_all);
  k2_features<<<dim3(256, 2), 256, 0, stream>>>(x4, x3, Wf, bias_all, Qf8, Kf8, V);
  k3_smax    <<<512,          512, 0, stream>>>(Qf8, Kf8, Pm);
  k5_out     <<<4096,         256, 0, stream>>>(V, Pm, b128, out);
}

// Round 7
// 184.437 us; speedup vs baseline: 1.0434x; 1.0011x over previous
//
#include <hip/hip_runtime.h>

typedef unsigned short ushort_t;
typedef unsigned char uchar_t;
typedef __attribute__((ext_vector_type(8))) short bf16x8;
typedef __attribute__((ext_vector_type(4))) float f32x4;
typedef __attribute__((ext_vector_type(16))) float f32x16;
typedef __attribute__((ext_vector_type(8))) int v8i;

__device__ __forceinline__ unsigned short f2bf(float f) {
  union { float f; unsigned int u; } v; v.f = f;
  unsigned int r = v.u + 0x7FFFu + ((v.u >> 16) & 1u);
  return (unsigned short)(r >> 16);
}

__device__ __forceinline__ float bf2f(unsigned short u) {
  union { unsigned int i; float f; } v; v.i = ((unsigned int)u) << 16;
  return v.f;
}

__device__ __forceinline__ void gl_lds16(const void* gsrc, void* ldst) {
  __builtin_amdgcn_global_load_lds(
      (const __attribute__((address_space(1))) void*)gsrc,
      (__attribute__((address_space(3))) void*)ldst, 16, 0, 0);
}

__device__ __forceinline__ int frag_idx(int oc, int ci) {
  return (((oc>>4)*8 + (ci>>5))<<9) + ((((ci>>3)&3)*16 + (oc&15))<<3) + (ci&7);
}

// ---------------------------------------------------------------------------
// K1: fragment-major bf16 weight bank Wf[640][256] (Q=wq, K=wk, V=w128@wv)
//     + bias_all[640].  Blocks 0..511: copy/cast QK.  512..639: V-fold, 1 oc
//     per block.
// ---------------------------------------------------------------------------
__global__ __launch_bounds__(256) void k1_weights(
    const float* __restrict__ wq, const float* __restrict__ bq,
    const float* __restrict__ wk, const float* __restrict__ bk,
    const float* __restrict__ wv, const float* __restrict__ bv,
    const float* __restrict__ w128,
    ushort_t* __restrict__ Wf, float* __restrict__ bias_all)
{
  const int ci = threadIdx.x;
  const int oc = blockIdx.x;
  if (oc < 512) {
    const float v = (oc < 256) ? wq[oc*256 + ci] : wk[(oc-256)*256 + ci];
    Wf[frag_idx(oc, ci)] = f2bf(v);
    if (ci == 0) bias_all[oc] = (oc < 256) ? bq[oc] : bk[oc-256];
  } else {
    const int o = oc - 512;
    const float* wr = w128 + (size_t)o*256;
    float a = 0.f;
    for (int co = 0; co < 256; co++) a += wr[co] * wv[co*256 + ci];
    Wf[frag_idx(oc, ci)] = f2bf(a);
    if (ci == 0) {
      float s = 0.f;
      for (int co = 0; co < 256; co++) s += wr[co] * bv[co];
      bias_all[oc] = s;
    }
  }
}

// ---------------------------------------------------------------------------
// K2: MFMA feature GEMM (bf16 16x16x32 internally). Grid (256, 2):
//   x = 64-px tile, y splits the output dim: y=0 -> ot 0..4, y=1 -> ot 5..9.
//   ot 0..3 -> Qf8, 4..7 -> Kf8 (fp8 e4m3 chunks, 1 KB each, 16B/lane),
//   ot 8..9 -> V fp32 [src*8+b][oc][hw]
//   R4: vmcnt(8) -> vmcnt(32): waits exactly the previous ot's 32 loads
//   (oldest-first), keeping the just-issued next-ot prefetch in flight.
// ---------------------------------------------------------------------------
__global__ __launch_bounds__(256) void k2_features(
    const float* __restrict__ x4, const float* __restrict__ x3,
    const ushort_t* __restrict__ Wf, const float* __restrict__ bias_all,
    uchar_t* __restrict__ Qf8, uchar_t* __restrict__ Kf8, float* __restrict__ V)
{
  __shared__ ushort_t Af[32*512];      // 32 KB
  __shared__ ushort_t Wl[2][32*512];   // 2 x 32 KB
  __shared__ ushort_t Lt[64*72];       // repack buffer (bf16)

  const int tid = threadIdx.x;
  const int w = tid >> 6, lane = tid & 63;
  const int mrow = lane & 15, quad = lane >> 4;
  const int ln31 = lane & 31, half = lane >> 5;

  const int px0 = blockIdx.x * 64;
  const int src = px0 >> 13, b = (px0 >> 10) & 7, hw0 = px0 & 1023;
  const float* xp = (src ? x3 : x4) + (size_t)b*262144;

  const int ot0 = blockIdx.y * 5;      // y=0: ot 0..4, y=1: ot 5..9

  for (int kb = 0; kb < 8; kb++)
    gl_lds16(Wf + ((size_t)((ot0*4 + w)*8 + kb)<<9) + lane*8,
             &Wl[ot0&1][(w*8+kb)*512]);

  {
    const int hw = hw0 + w*16 + mrow;
    for (int kb = 0; kb < 8; kb++) {
      const int ch0 = kb*32 + quad*8;
      bf16x8 pk;
      #pragma unroll
      for (int j = 0; j < 8; j++)
        ((ushort_t*)&pk)[j] = f2bf(xp[(size_t)(ch0 + j)*1024 + hw]);
      *(bf16x8*)&Af[(w*8 + kb)*512 + lane*8] = pk;
    }
  }
  __syncthreads();

  for (int ot = ot0; ot < ot0 + 5; ot++) {
    const int nbuf = (ot+1) & 1, cbuf = ot & 1;
    if (ot + 1 < ot0 + 5) {
      for (int kb = 0; kb < 8; kb++)
        gl_lds16(Wf + ((size_t)(((ot+1)*4 + w)*8 + kb)<<9) + lane*8,
                 &Wl[nbuf][(w*8+kb)*512]);
      asm volatile("s_waitcnt vmcnt(32)" ::: "memory");
    } else {
      asm volatile("s_waitcnt vmcnt(0)" ::: "memory");
    }

    f32x4 acc[4];
    #pragma unroll
    for (int lg = 0; lg < 4; lg++) acc[lg] = (f32x4){0.f,0.f,0.f,0.f};
    #pragma unroll
    for (int kb = 0; kb < 8; kb++) {
      const bf16x8 a = *(const bf16x8*)&Wl[cbuf][(w*8 + kb)*512 + lane*8];
      #pragma unroll
      for (int lg = 0; lg < 4; lg++) {
        const bf16x8 bx = *(const bf16x8*)&Af[(lg*8 + kb)*512 + lane*8];
        acc[lg] = __builtin_amdgcn_mfma_f32_16x16x32_bf16(a, bx, acc[lg], 0, 0, 0);
      }
    }
    const int ocl = w*16 + quad*4;
    const float4 bias4 = *(const float4*)&bias_all[ot*64 + ocl];

    if (ot < 8) {
      __syncthreads();
      #pragma unroll
      for (int lg = 0; lg < 4; lg++) {
        const int px = lg*16 + mrow;
        ushort4 pk;
        pk.x = f2bf(acc[lg][0] + bias4.x);
        pk.y = f2bf(acc[lg][1] + bias4.y);
        pk.z = f2bf(acc[lg][2] + bias4.z);
        pk.w = f2bf(acc[lg][3] + bias4.w);
        *(ushort4*)&Lt[px*72 + ocl] = pk;
      }
      __syncthreads();
      // emit one fp8 chunk per wave: wave w -> g = w>>1, e = w&1
      const int g = w >> 1, e = w & 1;
      const int row = g*32 + ln31;
      const ushort_t* lp = &Lt[row*72 + e*32 + half*8];
      float fl[8], fh[8];
      #pragma unroll
      for (int j = 0; j < 8; j++) { fl[j] = bf2f(lp[j]); fh[j] = bf2f(lp[16+j]); }
      int w0 = __builtin_amdgcn_cvt_pk_fp8_f32(fl[0], fl[1], 0, 0);
      w0     = __builtin_amdgcn_cvt_pk_fp8_f32(fl[2], fl[3], w0, 1);
      int w1 = __builtin_amdgcn_cvt_pk_fp8_f32(fl[4], fl[5], 0, 0);
      w1     = __builtin_amdgcn_cvt_pk_fp8_f32(fl[6], fl[7], w1, 1);
      int w2 = __builtin_amdgcn_cvt_pk_fp8_f32(fh[0], fh[1], 0, 0);
      w2     = __builtin_amdgcn_cvt_pk_fp8_f32(fh[2], fh[3], w2, 1);
      int w3 = __builtin_amdgcn_cvt_pk_fp8_f32(fh[4], fh[5], 0, 0);
      w3     = __builtin_amdgcn_cvt_pk_fp8_f32(fh[6], fh[7], w3, 1);
      uchar_t* dst = (ot < 4) ? Qf8 : Kf8;
      const size_t chunk = (size_t)((px0>>5) + g)*8 + (ot&3)*2 + e;
      int4 pk4; pk4.x = w0; pk4.y = w1; pk4.z = w2; pk4.w = w3;
      *(int4*)(dst + (chunk<<10) + lane*16) = pk4;
    } else {
      const int ocv0 = (ot-8)*64 + ocl;
      float* vb = V + (((size_t)(src*8 + b)*128) << 10) + hw0;
      #pragma unroll
      for (int lg = 0; lg < 4; lg++) {
        vb[(size_t)(ocv0+0)*1024 + lg*16 + mrow] = acc[lg][0] + bias4.x;
        vb[(size_t)(ocv0+1)*1024 + lg*16 + mrow] = acc[lg][1] + bias4.y;
        vb[(size_t)(ocv0+2)*1024 + lg*16 + mrow] = acc[lg][2] + bias4.z;
        vb[(size_t)(ocv0+3)*1024 + lg*16 + mrow] = acc[lg][3] + bias4.w;
      }
    }
  }
}

// ---------------------------------------------------------------------------
// K3: MX-scaled fp8 MFMA 32x32x64 (unit scales = plain fp8 at 2x rate).
//   Block = 512 rows x one key-batch (1024 cols), 8 waves x 64 rows (2 rg32),
//   2 waves/SIMD, LDS double-buffered 2x32KB, __syncthreads stage loop,
//   stage loop ROLLED (R3: full unroll -> 50MB spill.  R6: raw s_barrier
//   schedule -> 450x outlier dispatch; reverted).
//   R7: copy-free ds_read READ-AHEAD.  R3 allocated only 128 VGPR (live set
//   qa64+acc32+rmax32 = 128, zero headroom), so every cgl's 8 LDS reads
//   drained lgkmcnt->0 right before their MFMA burst: port (~220cy) fully
//   serial with pipe (~550cy), 32x per block = the missing ~40% MfmaUtil.
//   Now two fragment sets alternate with NO rename copies (R4's mistake):
//     rd(fA,c0) rd(fB,c1) | mfma(fA) rd(fA,c2) | mfma(fB) rd(fB,c3)
//     | mfma(fA) | mfma(fB)
//   Each read batch is issued one full MFMA burst before use -> port+latency
//   hidden.  Forces ~192-230 live regs (fits 256 @ 2 waves/SIMD, no spill).
//   No setprio (R4/m190: null-to-negative here).
//   Pm layout: [batch(16)][row(16384)].  Grid 512 x 512 threads.
// ---------------------------------------------------------------------------
#define RD8(FR, CGL)                                                        \
  _Pragma("unroll")                                                         \
  for (int t = 0; t < 8; t++)                                               \
    FR[t] = *(const int4*)&kl[((CGL)*8 + t)*1024 + lane*16];

#define QK_BURST(FR)                                                        \
  {                                                                         \
    f32x16 a0 = zv, a1 = zv;                                                \
    _Pragma("unroll")                                                       \
    for (int u = 0; u < 4; u++) {                                           \
      const v8i bu = (v8i){FR[2*u].x,   FR[2*u].y,   FR[2*u].z,   FR[2*u].w,\
                           FR[2*u+1].x, FR[2*u+1].y, FR[2*u+1].z, FR[2*u+1].w};\
      a0 = __builtin_amdgcn_mfma_scale_f32_32x32x64_f8f6f4(                 \
          qa[0][u], bu, a0, 0, 0, 0, 0x7F7F7F7F, 0, 0x7F7F7F7F);            \
      a1 = __builtin_amdgcn_mfma_scale_f32_32x32x64_f8f6f4(                 \
          qa[1][u], bu, a1, 0, 0, 0, 0x7F7F7F7F, 0, 0x7F7F7F7F);            \
    }                                                                       \
    _Pragma("unroll")                                                       \
    for (int i = 0; i < 16; i++) {                                          \
      rmax[0][i] = fmaxf(rmax[0][i], a0[i]);                                \
      rmax[1][i] = fmaxf(rmax[1][i], a1[i]);                                \
    }                                                                       \
  }

__global__ __launch_bounds__(512, 2) void k3_smax(
    const uchar_t* __restrict__ Qf8, const uchar_t* __restrict__ Kf8,
    float* __restrict__ Pm)
{
  __shared__ __align__(16) uchar_t Kl[2][32768];   // 2 x 32 KB

  const int tid = threadIdx.x;
  const int bt = blockIdx.x >> 5;      // key-batch 0..15
  const int rt = blockIdx.x & 31;      // row-tile (512 rows)
  const int w = tid >> 6, lane = tid & 63;   // w: 0..7
  const int ln31 = lane & 31, half = lane >> 5;

  const int rgb = rt*16 + w*2;         // wave's first row-grp32 (owns 2)
  const int ph = (blockIdx.x & 1)*4;   // stage-phase rotation (8 stages)

  // prologue: stage s=0: 32 chunks (4 cgl x 8 kp); wave w -> c = w*4..w*4+3
  #pragma unroll
  for (int q = 0; q < 4; q++) {
    const int c = w*4 + q;             // cgl = c>>3, kp = c&7
    const int cg = bt*32 + ph*4 + (c>>3);
    gl_lds16(Kf8 + (((size_t)cg*8 + (c&7))<<10) + lane*16, &Kl[0][c*1024]);
  }

  // Q fragments: 2 rg x 4 u-windows, v8i each (64 VGPR), resident whole kernel
  v8i qa[2][4];
  #pragma unroll
  for (int rg = 0; rg < 2; rg++)
    #pragma unroll
    for (int u = 0; u < 4; u++) {
      const int4 p0 = *(const int4*)(Qf8 + (((size_t)(rgb + rg)*8 + 2*u+0)<<10) + lane*16);
      const int4 p1 = *(const int4*)(Qf8 + (((size_t)(rgb + rg)*8 + 2*u+1)<<10) + lane*16);
      qa[rg][u] = (v8i){p0.x, p0.y, p0.z, p0.w, p1.x, p1.y, p1.z, p1.w};
    }

  f32x16 zv;
  #pragma unroll
  for (int i = 0; i < 16; i++) zv[i] = 0.f;
  f32x16 rmax[2];
  #pragma unroll
  for (int rg = 0; rg < 2; rg++)
    #pragma unroll
    for (int i = 0; i < 16; i++) rmax[rg][i] = -3.4e38f;

  #pragma unroll 1                      // KEEP ROLLED (R3: unroll -> spill)
  for (int s = 0; s < 8; s++) {
    __syncthreads();                   // drains prefetch for stage s
    if (s < 7) {
      const int sn = (s + 1 + ph) & 7;
      #pragma unroll
      for (int q = 0; q < 4; q++) {
        const int c = w*4 + q;
        const int cg = bt*32 + sn*4 + (c>>3);
        gl_lds16(Kf8 + (((size_t)cg*8 + (c&7))<<10) + lane*16,
                 &Kl[(s+1)&1][c*1024]);
      }
    }
    const uchar_t* kl = Kl[s & 1];

    int4 fA[8], fB[8];
    RD8(fA, 0)                         // reads for cgl 0
    RD8(fB, 1)                         // reads for cgl 1 (1 burst ahead)
    QK_BURST(fA)                       // cgl 0
    RD8(fA, 2)                         // reads for cgl 2
    QK_BURST(fB)                       // cgl 1
    RD8(fB, 3)                         // reads for cgl 3
    QK_BURST(fA)                       // cgl 2
    QK_BURST(fB)                       // cgl 3
  }

  // epilogue: per-row max over 32 cols (5 xor-shuffles in each 32-lane half)
  // C/D: col = lane&31, row = (reg&3) + 8*(reg>>2) + 4*half (shape-determined)
  #pragma unroll
  for (int rg = 0; rg < 2; rg++) {
    #pragma unroll
    for (int e = 0; e < 16; e++) {
      float v = rmax[rg][e];
      v = fmaxf(v, __shfl_xor(v, 1));
      v = fmaxf(v, __shfl_xor(v, 2));
      v = fmaxf(v, __shfl_xor(v, 4));
      v = fmaxf(v, __shfl_xor(v, 8));
      v = fmaxf(v, __shfl_xor(v, 16));
      if (ln31 == 0) {
        const int row = rt*512 + w*64 + rg*32 + (e&3) + 8*(e>>2) + 4*half;
        Pm[(size_t)bt*16384 + row] = v;
      }
    }
  }
}

// ---------------------------------------------------------------------------
// K5: fused gates + output.  Block = one (b, ch) pair, 256 threads x 4 hw.
//   Recomputes its gate row's softmax from Pm (deterministic, identical across
//   blocks sharing the row): logits = mean over 8 batch-maxes * scale.
//   out[b][ch][hw] = softmax_hw(logit) * V + b128.  ch: [x34|a_x4|x43|b_x3]
// ---------------------------------------------------------------------------
__global__ __launch_bounds__(256) void k5_out(
    const float* __restrict__ V, const float* __restrict__ Pm,
    const float* __restrict__ b128, float* __restrict__ out)
{
  __shared__ float xw[2][4];
  const int tid = threadIdx.x;
  const int ch = blockIdx.x & 511, b = blockIdx.x >> 9;
  const int blk = ch >> 7, o = ch & 127;
  const int gidx = (blk == 0) ? 2 : (blk == 1) ? 0 : (blk == 2) ? 1 : 3;
  const int src = (blk >= 2) ? 1 : 0;
  const int qset = gidx >> 1, side = gidx & 1;

  // logits for hw = tid*4 .. tid*4+3 (coalesced float4 per batch)
  const float4* Pm4 = (const float4*)(Pm + (size_t)side*8*16384 + qset*8192 + b*1024);
  float4 l = {0.f, 0.f, 0.f, 0.f};
  #pragma unroll
  for (int t = 0; t < 8; t++) {
    const float4 p = Pm4[t*4096 + tid];
    l.x += p.x; l.y += p.y; l.z += p.z; l.w += p.w;
  }
  const float sc = 0.125f * 0.0625f;   // mean over 8 batches * 1/sqrt(256)
  l.x *= sc; l.y *= sc; l.z *= sc; l.w *= sc;

  const int w = tid >> 6, lane = tid & 63;
  float m = fmaxf(fmaxf(l.x, l.y), fmaxf(l.z, l.w));
  #pragma unroll
  for (int d = 1; d < 64; d <<= 1) m = fmaxf(m, __shfl_xor(m, d));
  if (lane == 0) xw[0][w] = m;
  __syncthreads();
  m = fmaxf(fmaxf(xw[0][0], xw[0][1]), fmaxf(xw[0][2], xw[0][3]));

  float4 e;
  e.x = expf(l.x - m); e.y = expf(l.y - m);
  e.z = expf(l.z - m); e.w = expf(l.w - m);
  float s = e.x + e.y + e.z + e.w;
  #pragma unroll
  for (int d = 1; d < 64; d <<= 1) s += __shfl_xor(s, d);
  if (lane == 0) xw[1][w] = s;
  __syncthreads();
  s = xw[1][0] + xw[1][1] + xw[1][2] + xw[1][3];
  const float inv = 1.f / s;

  const int hw0 = tid << 2;
  const float4 v = *(const float4*)&V[((size_t)((src*8 + b)*128 + o) << 10) + hw0];
  const float bias = b128[o];
  float4 r;
  r.x = e.x*inv*v.x + bias; r.y = e.y*inv*v.y + bias;
  r.z = e.z*inv*v.z + bias; r.w = e.w*inv*v.w + bias;
  *(float4*)&out[((size_t)(b*512 + ch) << 10) + hw0] = r;
}

// ---------------------------------------------------------------------------
extern "C" void kernel_launch(void* const* d_in, const int* in_sizes, int n_in,
                              void* d_out, int out_size, void* d_ws, size_t ws_size,
                              hipStream_t stream)
{
  const float* x4   = (const float*)d_in[0];
  const float* x3   = (const float*)d_in[1];
  const float* wq   = (const float*)d_in[2];
  const float* bq   = (const float*)d_in[3];
  const float* wk   = (const float*)d_in[4];
  const float* bk   = (const float*)d_in[5];
  const float* wv   = (const float*)d_in[6];
  const float* bv   = (const float*)d_in[7];
  const float* w128 = (const float*)d_in[8];
  const float* b128 = (const float*)d_in[9];
  float* out = (float*)d_out;

  char* ws = (char*)d_ws;
  uchar_t*  Qf8 = (uchar_t*)ws;  ws += (size_t)512*8*1024;      // 4 MB
  uchar_t*  Kf8 = (uchar_t*)ws;  ws += (size_t)512*8*1024;      // 4 MB
  float*    V   = (float*)ws;    ws += (size_t)2*8*128*1024*4;  // 8 MB
  float*    Pm  = (float*)ws;    ws += (size_t)16*16384*4;      // 1 MB
  ushort_t* Wf  = (ushort_t*)ws; ws += (size_t)640*256*2;       // 320 KB
  float* bias_all = (float*)ws;                                 // 2.5 KB

  k1_weights <<<640,          256, 0, stream>>>(wq, bq, wk, bk, wv, bv, w128, Wf, bias_all);
  k2_features<<<dim3(256, 2), 256, 0, stream>>>(x4, x3, Wf, bias_all, Qf8, Kf8, V);
  k3_smax    <<<512,          512, 0, stream>>>(Qf8, Kf8, Pm);
  k5_out     <<<4096,         256, 0, stream>>>(V, Pm, b128, out);
}

// Round 8
// 179.347 us; speedup vs baseline: 1.0730x; 1.0284x over previous
//
#include <hip/hip_runtime.h>

typedef unsigned short ushort_t;
typedef unsigned char uchar_t;
typedef __attribute__((ext_vector_type(8))) short bf16x8;
typedef __attribute__((ext_vector_type(4))) float f32x4;
typedef __attribute__((ext_vector_type(16))) float f32x16;
typedef __attribute__((ext_vector_type(8))) int v8i;
typedef __attribute__((ext_vector_type(4))) int v4i;

__device__ __forceinline__ unsigned short f2bf(float f) {
  union { float f; unsigned int u; } v; v.f = f;
  unsigned int r = v.u + 0x7FFFu + ((v.u >> 16) & 1u);
  return (unsigned short)(r >> 16);
}

__device__ __forceinline__ float bf2f(unsigned short u) {
  union { unsigned int i; float f; } v; v.i = ((unsigned int)u) << 16;
  return v.f;
}

__device__ __forceinline__ void gl_lds16(const void* gsrc, void* ldst) {
  __builtin_amdgcn_global_load_lds(
      (const __attribute__((address_space(1))) void*)gsrc,
      (__attribute__((address_space(3))) void*)ldst, 16, 0, 0);
}

__device__ __forceinline__ unsigned lds_addr(void* p) {
  return (unsigned)(uintptr_t)(__attribute__((address_space(3))) void*)p;
}

__device__ __forceinline__ int frag_idx(int oc, int ci) {
  return (((oc>>4)*8 + (ci>>5))<<9) + ((((ci>>3)&3)*16 + (oc&15))<<3) + (ci&7);
}

// ---------------------------------------------------------------------------
// K1: fragment-major bf16 weight bank Wf[640][256] (Q=wq, K=wk, V=w128@wv)
//     + bias_all[640].  Blocks 0..511: copy/cast QK.  512..639: V-fold, 1 oc
//     per block.
// ---------------------------------------------------------------------------
__global__ __launch_bounds__(256) void k1_weights(
    const float* __restrict__ wq, const float* __restrict__ bq,
    const float* __restrict__ wk, const float* __restrict__ bk,
    const float* __restrict__ wv, const float* __restrict__ bv,
    const float* __restrict__ w128,
    ushort_t* __restrict__ Wf, float* __restrict__ bias_all)
{
  const int ci = threadIdx.x;
  const int oc = blockIdx.x;
  if (oc < 512) {
    const float v = (oc < 256) ? wq[oc*256 + ci] : wk[(oc-256)*256 + ci];
    Wf[frag_idx(oc, ci)] = f2bf(v);
    if (ci == 0) bias_all[oc] = (oc < 256) ? bq[oc] : bk[oc-256];
  } else {
    const int o = oc - 512;
    const float* wr = w128 + (size_t)o*256;
    float a = 0.f;
    for (int co = 0; co < 256; co++) a += wr[co] * wv[co*256 + ci];
    Wf[frag_idx(oc, ci)] = f2bf(a);
    if (ci == 0) {
      float s = 0.f;
      for (int co = 0; co < 256; co++) s += wr[co] * bv[co];
      bias_all[oc] = s;
    }
  }
}

// ---------------------------------------------------------------------------
// K2: MFMA feature GEMM (bf16 16x16x32 internally). Grid (256, 2):
//   x = 64-px tile, y splits the output dim: y=0 -> ot 0..4, y=1 -> ot 5..9.
//   ot 0..3 -> Qf8, 4..7 -> Kf8 (fp8 e4m3 chunks, 1 KB each, 16B/lane),
//   ot 8..9 -> V fp32 [src*8+b][oc][hw]
//   R4: vmcnt(8) -> vmcnt(32): waits exactly the previous ot's 32 loads
//   (oldest-first), keeping the just-issued next-ot prefetch in flight.
// ---------------------------------------------------------------------------
__global__ __launch_bounds__(256) void k2_features(
    const float* __restrict__ x4, const float* __restrict__ x3,
    const ushort_t* __restrict__ Wf, const float* __restrict__ bias_all,
    uchar_t* __restrict__ Qf8, uchar_t* __restrict__ Kf8, float* __restrict__ V)
{
  __shared__ ushort_t Af[32*512];      // 32 KB
  __shared__ ushort_t Wl[2][32*512];   // 2 x 32 KB
  __shared__ ushort_t Lt[64*72];       // repack buffer (bf16)

  const int tid = threadIdx.x;
  const int w = tid >> 6, lane = tid & 63;
  const int mrow = lane & 15, quad = lane >> 4;
  const int ln31 = lane & 31, half = lane >> 5;

  const int px0 = blockIdx.x * 64;
  const int src = px0 >> 13, b = (px0 >> 10) & 7, hw0 = px0 & 1023;
  const float* xp = (src ? x3 : x4) + (size_t)b*262144;

  const int ot0 = blockIdx.y * 5;      // y=0: ot 0..4, y=1: ot 5..9

  for (int kb = 0; kb < 8; kb++)
    gl_lds16(Wf + ((size_t)((ot0*4 + w)*8 + kb)<<9) + lane*8,
             &Wl[ot0&1][(w*8+kb)*512]);

  {
    const int hw = hw0 + w*16 + mrow;
    for (int kb = 0; kb < 8; kb++) {
      const int ch0 = kb*32 + quad*8;
      bf16x8 pk;
      #pragma unroll
      for (int j = 0; j < 8; j++)
        ((ushort_t*)&pk)[j] = f2bf(xp[(size_t)(ch0 + j)*1024 + hw]);
      *(bf16x8*)&Af[(w*8 + kb)*512 + lane*8] = pk;
    }
  }
  __syncthreads();

  for (int ot = ot0; ot < ot0 + 5; ot++) {
    const int nbuf = (ot+1) & 1, cbuf = ot & 1;
    if (ot + 1 < ot0 + 5) {
      for (int kb = 0; kb < 8; kb++)
        gl_lds16(Wf + ((size_t)(((ot+1)*4 + w)*8 + kb)<<9) + lane*8,
                 &Wl[nbuf][(w*8+kb)*512]);
      asm volatile("s_waitcnt vmcnt(32)" ::: "memory");
    } else {
      asm volatile("s_waitcnt vmcnt(0)" ::: "memory");
    }

    f32x4 acc[4];
    #pragma unroll
    for (int lg = 0; lg < 4; lg++) acc[lg] = (f32x4){0.f,0.f,0.f,0.f};
    #pragma unroll
    for (int kb = 0; kb < 8; kb++) {
      const bf16x8 a = *(const bf16x8*)&Wl[cbuf][(w*8 + kb)*512 + lane*8];
      #pragma unroll
      for (int lg = 0; lg < 4; lg++) {
        const bf16x8 bx = *(const bf16x8*)&Af[(lg*8 + kb)*512 + lane*8];
        acc[lg] = __builtin_amdgcn_mfma_f32_16x16x32_bf16(a, bx, acc[lg], 0, 0, 0);
      }
    }
    const int ocl = w*16 + quad*4;
    const float4 bias4 = *(const float4*)&bias_all[ot*64 + ocl];

    if (ot < 8) {
      __syncthreads();
      #pragma unroll
      for (int lg = 0; lg < 4; lg++) {
        const int px = lg*16 + mrow;
        ushort4 pk;
        pk.x = f2bf(acc[lg][0] + bias4.x);
        pk.y = f2bf(acc[lg][1] + bias4.y);
        pk.z = f2bf(acc[lg][2] + bias4.z);
        pk.w = f2bf(acc[lg][3] + bias4.w);
        *(ushort4*)&Lt[px*72 + ocl] = pk;
      }
      __syncthreads();
      // emit one fp8 chunk per wave: wave w -> g = w>>1, e = w&1
      const int g = w >> 1, e = w & 1;
      const int row = g*32 + ln31;
      const ushort_t* lp = &Lt[row*72 + e*32 + half*8];
      float fl[8], fh[8];
      #pragma unroll
      for (int j = 0; j < 8; j++) { fl[j] = bf2f(lp[j]); fh[j] = bf2f(lp[16+j]); }
      int w0 = __builtin_amdgcn_cvt_pk_fp8_f32(fl[0], fl[1], 0, 0);
      w0     = __builtin_amdgcn_cvt_pk_fp8_f32(fl[2], fl[3], w0, 1);
      int w1 = __builtin_amdgcn_cvt_pk_fp8_f32(fl[4], fl[5], 0, 0);
      w1     = __builtin_amdgcn_cvt_pk_fp8_f32(fl[6], fl[7], w1, 1);
      int w2 = __builtin_amdgcn_cvt_pk_fp8_f32(fh[0], fh[1], 0, 0);
      w2     = __builtin_amdgcn_cvt_pk_fp8_f32(fh[2], fh[3], w2, 1);
      int w3 = __builtin_amdgcn_cvt_pk_fp8_f32(fh[4], fh[5], 0, 0);
      w3     = __builtin_amdgcn_cvt_pk_fp8_f32(fh[6], fh[7], w3, 1);
      uchar_t* dst = (ot < 4) ? Qf8 : Kf8;
      const size_t chunk = (size_t)((px0>>5) + g)*8 + (ot&3)*2 + e;
      int4 pk4; pk4.x = w0; pk4.y = w1; pk4.z = w2; pk4.w = w3;
      *(int4*)(dst + (chunk<<10) + lane*16) = pk4;
    } else {
      const int ocv0 = (ot-8)*64 + ocl;
      float* vb = V + (((size_t)(src*8 + b)*128) << 10) + hw0;
      #pragma unroll
      for (int lg = 0; lg < 4; lg++) {
        vb[(size_t)(ocv0+0)*1024 + lg*16 + mrow] = acc[lg][0] + bias4.x;
        vb[(size_t)(ocv0+1)*1024 + lg*16 + mrow] = acc[lg][1] + bias4.y;
        vb[(size_t)(ocv0+2)*1024 + lg*16 + mrow] = acc[lg][2] + bias4.z;
        vb[(size_t)(ocv0+3)*1024 + lg*16 + mrow] = acc[lg][3] + bias4.w;
      }
    }
  }
}

// ---------------------------------------------------------------------------
// K3: MX-scaled fp8 MFMA 32x32x64 (unit scales = plain fp8 at 2x rate).
//   Block = 512 rows x one key-batch (1024 cols), 8 waves x 64 rows (2 rg32),
//   2 waves/SIMD, LDS double-buffered 2x32KB, __syncthreads stage loop,
//   stage loop ROLLED (R3: full unroll -> 50MB spill).
//   R8: ASM-PINNED ds_read pipeline (rule #18).  R7's plain-load read-ahead
//   was sunk by the allocator (VGPR stayed 128, dur stayed 65us) -- plain LDS
//   loads are freely sinkable.  Now reads are asm volatile ds_read_b128
//   (base VGPR + imm offset), gated by counted s_waitcnt lgkmcnt(8) (drains
//   exactly the PREVIOUS 8-read set, leaves the new 8 in flight; LDS
//   completes in-order) + sched_barrier(0) fences that pin each MFMA burst
//   between its gate and the next (bursts cannot hoist above the fence, so
//   cgl c+1's reads always issue before burst c).  Last cgl gates lgkmcnt(0)
//   so loop-top __syncthreads sees a clean counter.  Forced liveness ~200
//   regs (fB live across burst(fA) by construction) <= 256 @ 2 waves/SIMD.
//   Model: stage 19.5K cy serial -> 1.5K pile-up + 4x2.2K bursts ~= 10.3K.
//   Pm layout: [batch(16)][row(16384)].  Grid 512 x 512 threads.
// ---------------------------------------------------------------------------
#define RD8A(FR, CGL)                                                       \
  _Pragma("unroll")                                                         \
  for (int t = 0; t < 8; t++)                                               \
    asm volatile("ds_read_b128 %0, %1 offset:%c2"                           \
                 : "=v"(FR[t]) : "v"(kb), "i"((CGL)*8192 + t*1024));

#define WAITK(N)                                                            \
  asm volatile("s_waitcnt lgkmcnt(" #N ")" ::: "memory");                   \
  __builtin_amdgcn_sched_barrier(0);

#define QK_BURST(FR)                                                        \
  {                                                                         \
    f32x16 a0 = zv, a1 = zv;                                                \
    _Pragma("unroll")                                                       \
    for (int u = 0; u < 4; u++) {                                           \
      const v8i bu = (v8i){FR[2*u][0],   FR[2*u][1],   FR[2*u][2],   FR[2*u][3], \
                           FR[2*u+1][0], FR[2*u+1][1], FR[2*u+1][2], FR[2*u+1][3]}; \
      a0 = __builtin_amdgcn_mfma_scale_f32_32x32x64_f8f6f4(                 \
          qa[0][u], bu, a0, 0, 0, 0, 0x7F7F7F7F, 0, 0x7F7F7F7F);            \
      a1 = __builtin_amdgcn_mfma_scale_f32_32x32x64_f8f6f4(                 \
          qa[1][u], bu, a1, 0, 0, 0, 0x7F7F7F7F, 0, 0x7F7F7F7F);            \
    }                                                                       \
    _Pragma("unroll")                                                       \
    for (int i = 0; i < 16; i++) {                                          \
      rmax[0][i] = fmaxf(rmax[0][i], a0[i]);                                \
      rmax[1][i] = fmaxf(rmax[1][i], a1[i]);                                \
    }                                                                       \
  }

__global__ __launch_bounds__(512, 2) void k3_smax(
    const uchar_t* __restrict__ Qf8, const uchar_t* __restrict__ Kf8,
    float* __restrict__ Pm)
{
  __shared__ __align__(16) uchar_t Kl[2][32768];   // 2 x 32 KB

  const int tid = threadIdx.x;
  const int bt = blockIdx.x >> 5;      // key-batch 0..15
  const int rt = blockIdx.x & 31;      // row-tile (512 rows)
  const int w = tid >> 6, lane = tid & 63;   // w: 0..7
  const int ln31 = lane & 31, half = lane >> 5;

  const int rgb = rt*16 + w*2;         // wave's first row-grp32 (owns 2)
  const int ph = (blockIdx.x & 1)*4;   // stage-phase rotation (8 stages)

  // prologue: stage s=0: 32 chunks (4 cgl x 8 kp); wave w -> c = w*4..w*4+3
  #pragma unroll
  for (int q = 0; q < 4; q++) {
    const int c = w*4 + q;             // cgl = c>>3, kp = c&7
    const int cg = bt*32 + ph*4 + (c>>3);
    gl_lds16(Kf8 + (((size_t)cg*8 + (c&7))<<10) + lane*16, &Kl[0][c*1024]);
  }

  // Q fragments: 2 rg x 4 u-windows, v8i each (64 VGPR), resident whole kernel
  v8i qa[2][4];
  #pragma unroll
  for (int rg = 0; rg < 2; rg++)
    #pragma unroll
    for (int u = 0; u < 4; u++) {
      const int4 p0 = *(const int4*)(Qf8 + (((size_t)(rgb + rg)*8 + 2*u+0)<<10) + lane*16);
      const int4 p1 = *(const int4*)(Qf8 + (((size_t)(rgb + rg)*8 + 2*u+1)<<10) + lane*16);
      qa[rg][u] = (v8i){p0.x, p0.y, p0.z, p0.w, p1.x, p1.y, p1.z, p1.w};
    }

  f32x16 zv;
  #pragma unroll
  for (int i = 0; i < 16; i++) zv[i] = 0.f;
  f32x16 rmax[2];
  #pragma unroll
  for (int rg = 0; rg < 2; rg++)
    #pragma unroll
    for (int i = 0; i < 16; i++) rmax[rg][i] = -3.4e38f;

  const unsigned kb0 = lds_addr(&Kl[0][0]) + lane*16;
  const unsigned kb1 = lds_addr(&Kl[1][0]) + lane*16;

  #pragma unroll 1                      // KEEP ROLLED (R3: unroll -> spill)
  for (int s = 0; s < 8; s++) {
    __syncthreads();                   // stage s data visible; vmcnt drained
    if (s < 7) {
      const int sn = (s + 1 + ph) & 7;
      #pragma unroll
      for (int q = 0; q < 4; q++) {
        const int c = w*4 + q;
        const int cg = bt*32 + sn*4 + (c>>3);
        gl_lds16(Kf8 + (((size_t)cg*8 + (c&7))<<10) + lane*16,
                 &Kl[(s+1)&1][c*1024]);
      }
    }
    const unsigned kb = (s & 1) ? kb1 : kb0;

    v4i fA[8], fB[8];
    RD8A(fA, 0)                        // 8 outstanding
    RD8A(fB, 1)                        // 16 outstanding
    WAITK(8)                           // fA ready, fB in flight
    QK_BURST(fA)                       // cgl 0
    RD8A(fA, 2)                        // 16 outstanding (fB + fA')
    WAITK(8)                           // fB ready, fA' in flight
    QK_BURST(fB)                       // cgl 1
    RD8A(fB, 3)                        // 16 outstanding (fA' + fB')
    WAITK(8)                           // fA' ready, fB' in flight
    QK_BURST(fA)                       // cgl 2
    WAITK(0)                           // fB' ready; clean counter for barrier
    QK_BURST(fB)                       // cgl 3
  }

  // epilogue: per-row max over 32 cols (5 xor-shuffles in each 32-lane half)
  // C/D: col = lane&31, row = (reg&3) + 8*(reg>>2) + 4*half (shape-determined)
  #pragma unroll
  for (int rg = 0; rg < 2; rg++) {
    #pragma unroll
    for (int e = 0; e < 16; e++) {
      float v = rmax[rg][e];
      v = fmaxf(v, __shfl_xor(v, 1));
      v = fmaxf(v, __shfl_xor(v, 2));
      v = fmaxf(v, __shfl_xor(v, 4));
      v = fmaxf(v, __shfl_xor(v, 8));
      v = fmaxf(v, __shfl_xor(v, 16));
      if (ln31 == 0) {
        const int row = rt*512 + w*64 + rg*32 + (e&3) + 8*(e>>2) + 4*half;
        Pm[(size_t)bt*16384 + row] = v;
      }
    }
  }
}

// ---------------------------------------------------------------------------
// K5: fused gates + output.  Block = one (b, ch) pair, 256 threads x 4 hw.
//   Recomputes its gate row's softmax from Pm (deterministic, identical across
//   blocks sharing the row): logits = mean over 8 batch-maxes * scale.
//   out[b][ch][hw] = softmax_hw(logit) * V + b128.  ch: [x34|a_x4|x43|b_x3]
// ---------------------------------------------------------------------------
__global__ __launch_bounds__(256) void k5_out(
    const float* __restrict__ V, const float* __restrict__ Pm,
    const float* __restrict__ b128, float* __restrict__ out)
{
  __shared__ float xw[2][4];
  const int tid = threadIdx.x;
  const int ch = blockIdx.x & 511, b = blockIdx.x >> 9;
  const int blk = ch >> 7, o = ch & 127;
  const int gidx = (blk == 0) ? 2 : (blk == 1) ? 0 : (blk == 2) ? 1 : 3;
  const int src = (blk >= 2) ? 1 : 0;
  const int qset = gidx >> 1, side = gidx & 1;

  // logits for hw = tid*4 .. tid*4+3 (coalesced float4 per batch)
  const float4* Pm4 = (const float4*)(Pm + (size_t)side*8*16384 + qset*8192 + b*1024);
  float4 l = {0.f, 0.f, 0.f, 0.f};
  #pragma unroll
  for (int t = 0; t < 8; t++) {
    const float4 p = Pm4[t*4096 + tid];
    l.x += p.x; l.y += p.y; l.z += p.z; l.w += p.w;
  }
  const float sc = 0.125f * 0.0625f;   // mean over 8 batches * 1/sqrt(256)
  l.x *= sc; l.y *= sc; l.z *= sc; l.w *= sc;

  const int w = tid >> 6, lane = tid & 63;
  float m = fmaxf(fmaxf(l.x, l.y), fmaxf(l.z, l.w));
  #pragma unroll
  for (int d = 1; d < 64; d <<= 1) m = fmaxf(m, __shfl_xor(m, d));
  if (lane == 0) xw[0][w] = m;
  __syncthreads();
  m = fmaxf(fmaxf(xw[0][0], xw[0][1]), fmaxf(xw[0][2], xw[0][3]));

  float4 e;
  e.x = expf(l.x - m); e.y = expf(l.y - m);
  e.z = expf(l.z - m); e.w = expf(l.w - m);
  float s = e.x + e.y + e.z + e.w;
  #pragma unroll
  for (int d = 1; d < 64; d <<= 1) s += __shfl_xor(s, d);
  if (lane == 0) xw[1][w] = s;
  __syncthreads();
  s = xw[1][0] + xw[1][1] + xw[1][2] + xw[1][3];
  const float inv = 1.f / s;

  const int hw0 = tid << 2;
  const float4 v = *(const float4*)&V[((size_t)((src*8 + b)*128 + o) << 10) + hw0];
  const float bias = b128[o];
  float4 r;
  r.x = e.x*inv*v.x + bias; r.y = e.y*inv*v.y + bias;
  r.z = e.z*inv*v.z + bias; r.w = e.w*inv*v.w + bias;
  *(float4*)&out[((size_t)(b*512 + ch) << 10) + hw0] = r;
}

// ---------------------------------------------------------------------------
extern "C" void kernel_launch(void* const* d_in, const int* in_sizes, int n_in,
                              void* d_out, int out_size, void* d_ws, size_t ws_size,
                              hipStream_t stream)
{
  const float* x4   = (const float*)d_in[0];
  const float* x3   = (const float*)d_in[1];
  const float* wq   = (const float*)d_in[2];
  const float* bq   = (const float*)d_in[3];
  const float* wk   = (const float*)d_in[4];
  const float* bk   = (const float*)d_in[5];
  const float* wv   = (const float*)d_in[6];
  const float* bv   = (const float*)d_in[7];
  const float* w128 = (const float*)d_in[8];
  const float* b128 = (const float*)d_in[9];
  float* out = (float*)d_out;

  char* ws = (char*)d_ws;
  uchar_t*  Qf8 = (uchar_t*)ws;  ws += (size_t)512*8*1024;      // 4 MB
  uchar_t*  Kf8 = (uchar_t*)ws;  ws += (size_t)512*8*1024;      // 4 MB
  float*    V   = (float*)ws;    ws += (size_t)2*8*128*1024*4;  // 8 MB
  float*    Pm  = (float*)ws;    ws += (size_t)16*16384*4;      // 1 MB
  ushort_t* Wf  = (ushort_t*)ws; ws += (size_t)640*256*2;       // 320 KB
  float* bias_all = (float*)ws;                                 // 2.5 KB

  k1_weights <<<640,          256, 0, stream>>>(wq, bq, wk, bk, wv, bv, w128, Wf, bias_all);
  k2_features<<<dim3(256, 2), 256, 0, stream>>>(x4, x3, Wf, bias_all, Qf8, Kf8, V);
  k3_smax    <<<512,          512, 0, stream>>>(Qf8, Kf8, Pm);
  k5_out     <<<4096,         256, 0, stream>>>(V, Pm, b128, out);
}

// Round 9
// 179.015 us; speedup vs baseline: 1.0750x; 1.0019x over previous
//
#include <hip/hip_runtime.h>

typedef unsigned short ushort_t;
typedef unsigned char uchar_t;
typedef __attribute__((ext_vector_type(8))) short bf16x8;
typedef __attribute__((ext_vector_type(4))) float f32x4;
typedef __attribute__((ext_vector_type(16))) float f32x16;
typedef __attribute__((ext_vector_type(8))) int v8i;
typedef __attribute__((ext_vector_type(4))) int v4i;

__device__ __forceinline__ unsigned short f2bf(float f) {
  union { float f; unsigned int u; } v; v.f = f;
  unsigned int r = v.u + 0x7FFFu + ((v.u >> 16) & 1u);
  return (unsigned short)(r >> 16);
}

__device__ __forceinline__ float bf2f(unsigned short u) {
  union { unsigned int i; float f; } v; v.i = ((unsigned int)u) << 16;
  return v.f;
}

__device__ __forceinline__ void gl_lds16(const void* gsrc, void* ldst) {
  __builtin_amdgcn_global_load_lds(
      (const __attribute__((address_space(1))) void*)gsrc,
      (__attribute__((address_space(3))) void*)ldst, 16, 0, 0);
}

__device__ __forceinline__ unsigned lds_addr(void* p) {
  return (unsigned)(uintptr_t)(__attribute__((address_space(3))) void*)p;
}

__device__ __forceinline__ int frag_idx(int oc, int ci) {
  return (((oc>>4)*8 + (ci>>5))<<9) + ((((ci>>3)&3)*16 + (oc&15))<<3) + (ci&7);
}

// ---------------------------------------------------------------------------
// K1: fragment-major bf16 weight bank Wf[640][256] (Q=wq, K=wk, V=w128@wv)
//     + bias_all[640].  Blocks 0..511: copy/cast QK.  512..639: V-fold, 1 oc
//     per block.
// ---------------------------------------------------------------------------
__global__ __launch_bounds__(256) void k1_weights(
    const float* __restrict__ wq, const float* __restrict__ bq,
    const float* __restrict__ wk, const float* __restrict__ bk,
    const float* __restrict__ wv, const float* __restrict__ bv,
    const float* __restrict__ w128,
    ushort_t* __restrict__ Wf, float* __restrict__ bias_all)
{
  const int ci = threadIdx.x;
  const int oc = blockIdx.x;
  if (oc < 512) {
    const float v = (oc < 256) ? wq[oc*256 + ci] : wk[(oc-256)*256 + ci];
    Wf[frag_idx(oc, ci)] = f2bf(v);
    if (ci == 0) bias_all[oc] = (oc < 256) ? bq[oc] : bk[oc-256];
  } else {
    const int o = oc - 512;
    const float* wr = w128 + (size_t)o*256;
    float a = 0.f;
    for (int co = 0; co < 256; co++) a += wr[co] * wv[co*256 + ci];
    Wf[frag_idx(oc, ci)] = f2bf(a);
    if (ci == 0) {
      float s = 0.f;
      for (int co = 0; co < 256; co++) s += wr[co] * bv[co];
      bias_all[oc] = s;
    }
  }
}

// ---------------------------------------------------------------------------
// K2: MFMA feature GEMM (bf16 16x16x32 internally). Grid (256, 2):
//   x = 64-px tile, y splits the output dim: y=0 -> ot 0..4, y=1 -> ot 5..9.
//   ot 0..3 -> Qf8, 4..7 -> Kf8 (fp8 e4m3 chunks, 1 KB each, 16B/lane),
//   ot 8..9 -> V fp32 [src*8+b][oc][hw]
//   R4: vmcnt(8) -> vmcnt(32): waits exactly the previous ot's 32 loads
//   (oldest-first), keeping the just-issued next-ot prefetch in flight.
// ---------------------------------------------------------------------------
__global__ __launch_bounds__(256) void k2_features(
    const float* __restrict__ x4, const float* __restrict__ x3,
    const ushort_t* __restrict__ Wf, const float* __restrict__ bias_all,
    uchar_t* __restrict__ Qf8, uchar_t* __restrict__ Kf8, float* __restrict__ V)
{
  __shared__ ushort_t Af[32*512];      // 32 KB
  __shared__ ushort_t Wl[2][32*512];   // 2 x 32 KB
  __shared__ ushort_t Lt[64*72];       // repack buffer (bf16)

  const int tid = threadIdx.x;
  const int w = tid >> 6, lane = tid & 63;
  const int mrow = lane & 15, quad = lane >> 4;
  const int ln31 = lane & 31, half = lane >> 5;

  const int px0 = blockIdx.x * 64;
  const int src = px0 >> 13, b = (px0 >> 10) & 7, hw0 = px0 & 1023;
  const float* xp = (src ? x3 : x4) + (size_t)b*262144;

  const int ot0 = blockIdx.y * 5;      // y=0: ot 0..4, y=1: ot 5..9

  for (int kb = 0; kb < 8; kb++)
    gl_lds16(Wf + ((size_t)((ot0*4 + w)*8 + kb)<<9) + lane*8,
             &Wl[ot0&1][(w*8+kb)*512]);

  {
    const int hw = hw0 + w*16 + mrow;
    for (int kb = 0; kb < 8; kb++) {
      const int ch0 = kb*32 + quad*8;
      bf16x8 pk;
      #pragma unroll
      for (int j = 0; j < 8; j++)
        ((ushort_t*)&pk)[j] = f2bf(xp[(size_t)(ch0 + j)*1024 + hw]);
      *(bf16x8*)&Af[(w*8 + kb)*512 + lane*8] = pk;
    }
  }
  __syncthreads();

  for (int ot = ot0; ot < ot0 + 5; ot++) {
    const int nbuf = (ot+1) & 1, cbuf = ot & 1;
    if (ot + 1 < ot0 + 5) {
      for (int kb = 0; kb < 8; kb++)
        gl_lds16(Wf + ((size_t)(((ot+1)*4 + w)*8 + kb)<<9) + lane*8,
                 &Wl[nbuf][(w*8+kb)*512]);
      asm volatile("s_waitcnt vmcnt(32)" ::: "memory");
    } else {
      asm volatile("s_waitcnt vmcnt(0)" ::: "memory");
    }

    f32x4 acc[4];
    #pragma unroll
    for (int lg = 0; lg < 4; lg++) acc[lg] = (f32x4){0.f,0.f,0.f,0.f};
    #pragma unroll
    for (int kb = 0; kb < 8; kb++) {
      const bf16x8 a = *(const bf16x8*)&Wl[cbuf][(w*8 + kb)*512 + lane*8];
      #pragma unroll
      for (int lg = 0; lg < 4; lg++) {
        const bf16x8 bx = *(const bf16x8*)&Af[(lg*8 + kb)*512 + lane*8];
        acc[lg] = __builtin_amdgcn_mfma_f32_16x16x32_bf16(a, bx, acc[lg], 0, 0, 0);
      }
    }
    const int ocl = w*16 + quad*4;
    const float4 bias4 = *(const float4*)&bias_all[ot*64 + ocl];

    if (ot < 8) {
      __syncthreads();
      #pragma unroll
      for (int lg = 0; lg < 4; lg++) {
        const int px = lg*16 + mrow;
        ushort4 pk;
        pk.x = f2bf(acc[lg][0] + bias4.x);
        pk.y = f2bf(acc[lg][1] + bias4.y);
        pk.z = f2bf(acc[lg][2] + bias4.z);
        pk.w = f2bf(acc[lg][3] + bias4.w);
        *(ushort4*)&Lt[px*72 + ocl] = pk;
      }
      __syncthreads();
      // emit one fp8 chunk per wave: wave w -> g = w>>1, e = w&1
      const int g = w >> 1, e = w & 1;
      const int row = g*32 + ln31;
      const ushort_t* lp = &Lt[row*72 + e*32 + half*8];
      float fl[8], fh[8];
      #pragma unroll
      for (int j = 0; j < 8; j++) { fl[j] = bf2f(lp[j]); fh[j] = bf2f(lp[16+j]); }
      int w0 = __builtin_amdgcn_cvt_pk_fp8_f32(fl[0], fl[1], 0, 0);
      w0     = __builtin_amdgcn_cvt_pk_fp8_f32(fl[2], fl[3], w0, 1);
      int w1 = __builtin_amdgcn_cvt_pk_fp8_f32(fl[4], fl[5], 0, 0);
      w1     = __builtin_amdgcn_cvt_pk_fp8_f32(fl[6], fl[7], w1, 1);
      int w2 = __builtin_amdgcn_cvt_pk_fp8_f32(fh[0], fh[1], 0, 0);
      w2     = __builtin_amdgcn_cvt_pk_fp8_f32(fh[2], fh[3], w2, 1);
      int w3 = __builtin_amdgcn_cvt_pk_fp8_f32(fh[4], fh[5], 0, 0);
      w3     = __builtin_amdgcn_cvt_pk_fp8_f32(fh[6], fh[7], w3, 1);
      uchar_t* dst = (ot < 4) ? Qf8 : Kf8;
      const size_t chunk = (size_t)((px0>>5) + g)*8 + (ot&3)*2 + e;
      int4 pk4; pk4.x = w0; pk4.y = w1; pk4.z = w2; pk4.w = w3;
      *(int4*)(dst + (chunk<<10) + lane*16) = pk4;
    } else {
      const int ocv0 = (ot-8)*64 + ocl;
      float* vb = V + (((size_t)(src*8 + b)*128) << 10) + hw0;
      #pragma unroll
      for (int lg = 0; lg < 4; lg++) {
        vb[(size_t)(ocv0+0)*1024 + lg*16 + mrow] = acc[lg][0] + bias4.x;
        vb[(size_t)(ocv0+1)*1024 + lg*16 + mrow] = acc[lg][1] + bias4.y;
        vb[(size_t)(ocv0+2)*1024 + lg*16 + mrow] = acc[lg][2] + bias4.z;
        vb[(size_t)(ocv0+3)*1024 + lg*16 + mrow] = acc[lg][3] + bias4.w;
      }
    }
  }
}

// ---------------------------------------------------------------------------
// K3: MX-scaled fp8 MFMA 32x32x64 (unit scales = plain fp8 at 2x rate).
//   Block = 512 rows x one key-batch (1024 cols), 8 waves x 64 rows (2 rg32),
//   2 waves/SIMD, LDS double-buffered 2x32KB, __syncthreads stage loop,
//   stage loop ROLLED (R3: full unroll -> 50MB spill).
//   R8: asm-pinned ds_read pipeline, counted lgkmcnt(8) + sched_barrier(0)
//   (rule #18) -- reads for cgl c+1 always issue before burst c.  63.9us.
//   R9: + s_setprio(1) around each pinned MFMA burst (T5): the fenced
//   schedule gives the 2 waves/SIMD distinct roles (one reading, one in
//   MFMA) -> scheduler can favor the MFMA wave.  (R4's setprio test was
//   confounded by rename-copy VALU; this is the clean test.)
//   Pm layout: [batch(16)][row(16384)].  Grid 512 x 512 threads.
// ---------------------------------------------------------------------------
#define RD8A(FR, CGL)                                                       \
  _Pragma("unroll")                                                         \
  for (int t = 0; t < 8; t++)                                               \
    asm volatile("ds_read_b128 %0, %1 offset:%c2"                           \
                 : "=v"(FR[t]) : "v"(kb), "i"((CGL)*8192 + t*1024));

#define WAITK(N)                                                            \
  asm volatile("s_waitcnt lgkmcnt(" #N ")" ::: "memory");                   \
  __builtin_amdgcn_sched_barrier(0);

#define QK_BURST(FR)                                                        \
  {                                                                         \
    f32x16 a0 = zv, a1 = zv;                                                \
    __builtin_amdgcn_s_setprio(1);                                          \
    _Pragma("unroll")                                                       \
    for (int u = 0; u < 4; u++) {                                           \
      const v8i bu = (v8i){FR[2*u][0],   FR[2*u][1],   FR[2*u][2],   FR[2*u][3], \
                           FR[2*u+1][0], FR[2*u+1][1], FR[2*u+1][2], FR[2*u+1][3]}; \
      a0 = __builtin_amdgcn_mfma_scale_f32_32x32x64_f8f6f4(                 \
          qa[0][u], bu, a0, 0, 0, 0, 0x7F7F7F7F, 0, 0x7F7F7F7F);            \
      a1 = __builtin_amdgcn_mfma_scale_f32_32x32x64_f8f6f4(                 \
          qa[1][u], bu, a1, 0, 0, 0, 0x7F7F7F7F, 0, 0x7F7F7F7F);            \
    }                                                                       \
    __builtin_amdgcn_s_setprio(0);                                          \
    _Pragma("unroll")                                                       \
    for (int i = 0; i < 16; i++) {                                          \
      rmax[0][i] = fmaxf(rmax[0][i], a0[i]);                                \
      rmax[1][i] = fmaxf(rmax[1][i], a1[i]);                                \
    }                                                                       \
  }

__global__ __launch_bounds__(512, 2) void k3_smax(
    const uchar_t* __restrict__ Qf8, const uchar_t* __restrict__ Kf8,
    float* __restrict__ Pm)
{
  __shared__ __align__(16) uchar_t Kl[2][32768];   // 2 x 32 KB

  const int tid = threadIdx.x;
  const int bt = blockIdx.x >> 5;      // key-batch 0..15
  const int rt = blockIdx.x & 31;      // row-tile (512 rows)
  const int w = tid >> 6, lane = tid & 63;   // w: 0..7
  const int ln31 = lane & 31, half = lane >> 5;

  const int rgb = rt*16 + w*2;         // wave's first row-grp32 (owns 2)
  const int ph = (blockIdx.x & 1)*4;   // stage-phase rotation (8 stages)

  // prologue: stage s=0: 32 chunks (4 cgl x 8 kp); wave w -> c = w*4..w*4+3
  #pragma unroll
  for (int q = 0; q < 4; q++) {
    const int c = w*4 + q;             // cgl = c>>3, kp = c&7
    const int cg = bt*32 + ph*4 + (c>>3);
    gl_lds16(Kf8 + (((size_t)cg*8 + (c&7))<<10) + lane*16, &Kl[0][c*1024]);
  }

  // Q fragments: 2 rg x 4 u-windows, v8i each (64 VGPR), resident whole kernel
  v8i qa[2][4];
  #pragma unroll
  for (int rg = 0; rg < 2; rg++)
    #pragma unroll
    for (int u = 0; u < 4; u++) {
      const int4 p0 = *(const int4*)(Qf8 + (((size_t)(rgb + rg)*8 + 2*u+0)<<10) + lane*16);
      const int4 p1 = *(const int4*)(Qf8 + (((size_t)(rgb + rg)*8 + 2*u+1)<<10) + lane*16);
      qa[rg][u] = (v8i){p0.x, p0.y, p0.z, p0.w, p1.x, p1.y, p1.z, p1.w};
    }

  f32x16 zv;
  #pragma unroll
  for (int i = 0; i < 16; i++) zv[i] = 0.f;
  f32x16 rmax[2];
  #pragma unroll
  for (int rg = 0; rg < 2; rg++)
    #pragma unroll
    for (int i = 0; i < 16; i++) rmax[rg][i] = -3.4e38f;

  const unsigned kb0 = lds_addr(&Kl[0][0]) + lane*16;
  const unsigned kb1 = lds_addr(&Kl[1][0]) + lane*16;

  #pragma unroll 1                      // KEEP ROLLED (R3: unroll -> spill)
  for (int s = 0; s < 8; s++) {
    __syncthreads();                   // stage s data visible; vmcnt drained
    if (s < 7) {
      const int sn = (s + 1 + ph) & 7;
      #pragma unroll
      for (int q = 0; q < 4; q++) {
        const int c = w*4 + q;
        const int cg = bt*32 + sn*4 + (c>>3);
        gl_lds16(Kf8 + (((size_t)cg*8 + (c&7))<<10) + lane*16,
                 &Kl[(s+1)&1][c*1024]);
      }
    }
    const unsigned kb = (s & 1) ? kb1 : kb0;

    v4i fA[8], fB[8];
    RD8A(fA, 0)                        // 8 outstanding
    RD8A(fB, 1)                        // 16 outstanding
    WAITK(8)                           // fA ready, fB in flight
    QK_BURST(fA)                       // cgl 0
    RD8A(fA, 2)                        // 16 outstanding (fB + fA')
    WAITK(8)                           // fB ready, fA' in flight
    QK_BURST(fB)                       // cgl 1
    RD8A(fB, 3)                        // 16 outstanding (fA' + fB')
    WAITK(8)                           // fA' ready, fB' in flight
    QK_BURST(fA)                       // cgl 2
    WAITK(0)                           // fB' ready; clean counter for barrier
    QK_BURST(fB)                       // cgl 3
  }

  // epilogue: per-row max over 32 cols (5 xor-shuffles in each 32-lane half)
  // C/D: col = lane&31, row = (reg&3) + 8*(reg>>2) + 4*half (shape-determined)
  #pragma unroll
  for (int rg = 0; rg < 2; rg++) {
    #pragma unroll
    for (int e = 0; e < 16; e++) {
      float v = rmax[rg][e];
      v = fmaxf(v, __shfl_xor(v, 1));
      v = fmaxf(v, __shfl_xor(v, 2));
      v = fmaxf(v, __shfl_xor(v, 4));
      v = fmaxf(v, __shfl_xor(v, 8));
      v = fmaxf(v, __shfl_xor(v, 16));
      if (ln31 == 0) {
        const int row = rt*512 + w*64 + rg*32 + (e&3) + 8*(e>>2) + 4*half;
        Pm[(size_t)bt*16384 + row] = v;
      }
    }
  }
}

// ---------------------------------------------------------------------------
// K4 (NEW): the 32 distinct gate softmaxes, computed ONCE each.
//   Old k5 recomputed its row's softmax in all 4096 blocks (128x redundant:
//   8x1024 strided Pm reads + 2 barriered reductions per block = 128 MB of
//   L2 traffic).  Grid 32 = (b 8) x (gidx 4); SW[gidx][b][hw] = softmax
//   weight row.  ~1-2 us.
// ---------------------------------------------------------------------------
__global__ __launch_bounds__(256) void k4_smweights(
    const float* __restrict__ Pm, float* __restrict__ SW)
{
  __shared__ float xw[2][4];
  const int tid = threadIdx.x;
  const int b = blockIdx.x >> 2, gidx = blockIdx.x & 3;
  const int qset = gidx >> 1, side = gidx & 1;

  // logits for hw = tid*4 .. tid*4+3 (coalesced float4 per batch)
  const float4* Pm4 = (const float4*)(Pm + (size_t)side*8*16384 + qset*8192 + b*1024);
  float4 l = {0.f, 0.f, 0.f, 0.f};
  #pragma unroll
  for (int t = 0; t < 8; t++) {
    const float4 p = Pm4[t*4096 + tid];
    l.x += p.x; l.y += p.y; l.z += p.z; l.w += p.w;
  }
  const float sc = 0.125f * 0.0625f;   // mean over 8 batches * 1/sqrt(256)
  l.x *= sc; l.y *= sc; l.z *= sc; l.w *= sc;

  const int w = tid >> 6, lane = tid & 63;
  float m = fmaxf(fmaxf(l.x, l.y), fmaxf(l.z, l.w));
  #pragma unroll
  for (int d = 1; d < 64; d <<= 1) m = fmaxf(m, __shfl_xor(m, d));
  if (lane == 0) xw[0][w] = m;
  __syncthreads();
  m = fmaxf(fmaxf(xw[0][0], xw[0][1]), fmaxf(xw[0][2], xw[0][3]));

  float4 e;
  e.x = expf(l.x - m); e.y = expf(l.y - m);
  e.z = expf(l.z - m); e.w = expf(l.w - m);
  float s = e.x + e.y + e.z + e.w;
  #pragma unroll
  for (int d = 1; d < 64; d <<= 1) s += __shfl_xor(s, d);
  if (lane == 0) xw[1][w] = s;
  __syncthreads();
  s = xw[1][0] + xw[1][1] + xw[1][2] + xw[1][3];
  const float inv = 1.f / s;

  float4 r;
  r.x = e.x*inv; r.y = e.y*inv; r.z = e.z*inv; r.w = e.w*inv;
  *(float4*)&SW[((size_t)(gidx*8 + b) << 10) + (tid << 2)] = r;
}

// ---------------------------------------------------------------------------
// K5: pure streaming gate apply: out[b][ch][hw] = SW[gidx][b][hw] * V + b128.
//   Block = one (b, ch) pair, 256 threads x 1 float4.  Fully coalesced;
//   ~32 MB traffic -> ~5 us.  ch: [x34|a_x4|x43|b_x3]
// ---------------------------------------------------------------------------
__global__ __launch_bounds__(256) void k5_out(
    const float* __restrict__ V, const float* __restrict__ SW,
    const float* __restrict__ b128, float* __restrict__ out)
{
  const int tid = threadIdx.x;
  const int ch = blockIdx.x & 511, b = blockIdx.x >> 9;
  const int blk = ch >> 7, o = ch & 127;
  const int gidx = (blk == 0) ? 2 : (blk == 1) ? 0 : (blk == 2) ? 1 : 3;
  const int src = (blk >= 2) ? 1 : 0;

  const int hw0 = tid << 2;
  const float4 sw = *(const float4*)&SW[((size_t)(gidx*8 + b) << 10) + hw0];
  const float4 v = *(const float4*)&V[((size_t)((src*8 + b)*128 + o) << 10) + hw0];
  const float bias = b128[o];
  float4 r;
  r.x = sw.x*v.x + bias; r.y = sw.y*v.y + bias;
  r.z = sw.z*v.z + bias; r.w = sw.w*v.w + bias;
  *(float4*)&out[((size_t)(b*512 + ch) << 10) + hw0] = r;
}

// ---------------------------------------------------------------------------
extern "C" void kernel_launch(void* const* d_in, const int* in_sizes, int n_in,
                              void* d_out, int out_size, void* d_ws, size_t ws_size,
                              hipStream_t stream)
{
  const float* x4   = (const float*)d_in[0];
  const float* x3   = (const float*)d_in[1];
  const float* wq   = (const float*)d_in[2];
  const float* bq   = (const float*)d_in[3];
  const float* wk   = (const float*)d_in[4];
  const float* bk   = (const float*)d_in[5];
  const float* wv   = (const float*)d_in[6];
  const float* bv   = (const float*)d_in[7];
  const float* w128 = (const float*)d_in[8];
  const float* b128 = (const float*)d_in[9];
  float* out = (float*)d_out;

  char* ws = (char*)d_ws;
  uchar_t*  Qf8 = (uchar_t*)ws;  ws += (size_t)512*8*1024;      // 4 MB
  uchar_t*  Kf8 = (uchar_t*)ws;  ws += (size_t)512*8*1024;      // 4 MB
  float*    V   = (float*)ws;    ws += (size_t)2*8*128*1024*4;  // 8 MB
  float*    Pm  = (float*)ws;    ws += (size_t)16*16384*4;      // 1 MB
  ushort_t* Wf  = (ushort_t*)ws; ws += (size_t)640*256*2;       // 320 KB
  float* bias_all = (float*)ws;  ws += (size_t)640*4;           // 2.5 KB
  float* SW = (float*)ws;                                       // 128 KB

  k1_weights  <<<640,          256, 0, stream>>>(wq, bq, wk, bk, wv, bv, w128, Wf, bias_all);
  k2_features <<<dim3(256, 2), 256, 0, stream>>>(x4, x3, Wf, bias_all, Qf8, Kf8, V);
  k3_smax     <<<512,          512, 0, stream>>>(Qf8, Kf8, Pm);
  k4_smweights<<<32,           256, 0, stream>>>(Pm, SW);
  k5_out      <<<4096,         256, 0, stream>>>(V, SW, b128, out);
}

// Round 10
// 174.282 us; speedup vs baseline: 1.1042x; 1.0272x over previous
//
#include <hip/hip_runtime.h>

typedef unsigned short ushort_t;
typedef unsigned char uchar_t;
typedef __attribute__((ext_vector_type(8))) short bf16x8;
typedef __attribute__((ext_vector_type(4))) float f32x4;
typedef __attribute__((ext_vector_type(16))) float f32x16;
typedef __attribute__((ext_vector_type(8))) int v8i;
typedef __attribute__((ext_vector_type(4))) int v4i;

__device__ __forceinline__ unsigned short f2bf(float f) {
  union { float f; unsigned int u; } v; v.f = f;
  unsigned int r = v.u + 0x7FFFu + ((v.u >> 16) & 1u);
  return (unsigned short)(r >> 16);
}

__device__ __forceinline__ float bf2f(unsigned short u) {
  union { unsigned int i; float f; } v; v.i = ((unsigned int)u) << 16;
  return v.f;
}

__device__ __forceinline__ void gl_lds16(const void* gsrc, void* ldst) {
  __builtin_amdgcn_global_load_lds(
      (const __attribute__((address_space(1))) void*)gsrc,
      (__attribute__((address_space(3))) void*)ldst, 16, 0, 0);
}

__device__ __forceinline__ unsigned lds_addr(void* p) {
  return (unsigned)(uintptr_t)(__attribute__((address_space(3))) void*)p;
}

__device__ __forceinline__ int frag_idx(int oc, int ci) {
  return (((oc>>4)*8 + (ci>>5))<<9) + ((((ci>>3)&3)*16 + (oc&15))<<3) + (ci&7);
}

// ---------------------------------------------------------------------------
// K1: fragment-major bf16 weight bank Wf[640][256] (Q=wq, K=wk, V=w128@wv)
//     + bias_all[640].  Blocks 0..511: copy/cast QK.  512..639: V-fold, 1 oc
//     per block.
// ---------------------------------------------------------------------------
__global__ __launch_bounds__(256) void k1_weights(
    const float* __restrict__ wq, const float* __restrict__ bq,
    const float* __restrict__ wk, const float* __restrict__ bk,
    const float* __restrict__ wv, const float* __restrict__ bv,
    const float* __restrict__ w128,
    ushort_t* __restrict__ Wf, float* __restrict__ bias_all)
{
  const int ci = threadIdx.x;
  const int oc = blockIdx.x;
  if (oc < 512) {
    const float v = (oc < 256) ? wq[oc*256 + ci] : wk[(oc-256)*256 + ci];
    Wf[frag_idx(oc, ci)] = f2bf(v);
    if (ci == 0) bias_all[oc] = (oc < 256) ? bq[oc] : bk[oc-256];
  } else {
    const int o = oc - 512;
    const float* wr = w128 + (size_t)o*256;
    float a = 0.f;
    for (int co = 0; co < 256; co++) a += wr[co] * wv[co*256 + ci];
    Wf[frag_idx(oc, ci)] = f2bf(a);
    if (ci == 0) {
      float s = 0.f;
      for (int co = 0; co < 256; co++) s += wr[co] * bv[co];
      bias_all[oc] = s;
    }
  }
}

// ---------------------------------------------------------------------------
// K2: MFMA feature GEMM (bf16 16x16x32 internally).  Grid (256,1): one block
//   per 64-px tile runs ALL 10 output tiles (ot).
//   ot 0..3 -> Qf8, 4..7 -> Kf8 (fp8 e4m3 chunks), ot 8..9 -> V fp32.
//   R10: (a) Af B-fragments are ot-invariant -> hoisted to 128 VGPR ONCE per
//   wave (per-ot LDS reads drop 40 -> 8; they were re-read 10x before);
//   (b) grid.y removed: x staged + f2bf-converted ONCE (was twice), one
//   block-pass per CU instead of two.  LDS 105 KB -> 1 block/CU, so the
//   512-VGPR budget absorbs bb[4][8] without spill.  Values/order identical.
// ---------------------------------------------------------------------------
__global__ __launch_bounds__(256) void k2_features(
    const float* __restrict__ x4, const float* __restrict__ x3,
    const ushort_t* __restrict__ Wf, const float* __restrict__ bias_all,
    uchar_t* __restrict__ Qf8, uchar_t* __restrict__ Kf8, float* __restrict__ V)
{
  __shared__ ushort_t Af[32*512];      // 32 KB
  __shared__ ushort_t Wl[2][32*512];   // 2 x 32 KB
  __shared__ ushort_t Lt[64*72];       // repack buffer (bf16)

  const int tid = threadIdx.x;
  const int w = tid >> 6, lane = tid & 63;
  const int mrow = lane & 15, quad = lane >> 4;
  const int ln31 = lane & 31, half = lane >> 5;

  const int px0 = blockIdx.x * 64;
  const int src = px0 >> 13, b = (px0 >> 10) & 7, hw0 = px0 & 1023;
  const float* xp = (src ? x3 : x4) + (size_t)b*262144;

  // prologue: W-frags for ot=0 -> Wl[0]
  for (int kb = 0; kb < 8; kb++)
    gl_lds16(Wf + ((size_t)(w*8 + kb)<<9) + lane*8,
             &Wl[0][(w*8+kb)*512]);

  {
    const int hw = hw0 + w*16 + mrow;
    for (int kb = 0; kb < 8; kb++) {
      const int ch0 = kb*32 + quad*8;
      bf16x8 pk;
      #pragma unroll
      for (int j = 0; j < 8; j++)
        ((ushort_t*)&pk)[j] = f2bf(xp[(size_t)(ch0 + j)*1024 + hw]);
      *(bf16x8*)&Af[(w*8 + kb)*512 + lane*8] = pk;
    }
  }
  __syncthreads();

  // hoist B-fragments (ot-invariant) into registers: 32 x bf16x8 = 128 VGPR
  bf16x8 bb[4][8];
  #pragma unroll
  for (int lg = 0; lg < 4; lg++)
    #pragma unroll
    for (int kb = 0; kb < 8; kb++)
      bb[lg][kb] = *(const bf16x8*)&Af[(lg*8 + kb)*512 + lane*8];

  for (int ot = 0; ot < 10; ot++) {
    const int cbuf = ot & 1, nbuf = cbuf ^ 1;
    if (ot + 1 < 10) {
      for (int kb = 0; kb < 8; kb++)
        gl_lds16(Wf + ((size_t)(((ot+1)*4 + w)*8 + kb)<<9) + lane*8,
                 &Wl[nbuf][(w*8+kb)*512]);
      asm volatile("s_waitcnt vmcnt(8)" ::: "memory");
    } else {
      asm volatile("s_waitcnt vmcnt(0)" ::: "memory");
    }

    f32x4 acc[4];
    #pragma unroll
    for (int lg = 0; lg < 4; lg++) acc[lg] = (f32x4){0.f,0.f,0.f,0.f};
    #pragma unroll
    for (int kb = 0; kb < 8; kb++) {
      const bf16x8 a = *(const bf16x8*)&Wl[cbuf][(w*8 + kb)*512 + lane*8];
      #pragma unroll
      for (int lg = 0; lg < 4; lg++)
        acc[lg] = __builtin_amdgcn_mfma_f32_16x16x32_bf16(a, bb[lg][kb], acc[lg], 0, 0, 0);
    }
    const int ocl = w*16 + quad*4;
    const float4 bias4 = *(const float4*)&bias_all[ot*64 + ocl];

    if (ot < 8) {
      __syncthreads();
      #pragma unroll
      for (int lg = 0; lg < 4; lg++) {
        const int px = lg*16 + mrow;
        ushort4 pk;
        pk.x = f2bf(acc[lg][0] + bias4.x);
        pk.y = f2bf(acc[lg][1] + bias4.y);
        pk.z = f2bf(acc[lg][2] + bias4.z);
        pk.w = f2bf(acc[lg][3] + bias4.w);
        *(ushort4*)&Lt[px*72 + ocl] = pk;
      }
      __syncthreads();
      // emit one fp8 chunk per wave: wave w -> g = w>>1, e = w&1
      const int g = w >> 1, e = w & 1;
      const int row = g*32 + ln31;
      const ushort_t* lp = &Lt[row*72 + e*32 + half*8];
      float fl[8], fh[8];
      #pragma unroll
      for (int j = 0; j < 8; j++) { fl[j] = bf2f(lp[j]); fh[j] = bf2f(lp[16+j]); }
      int w0 = __builtin_amdgcn_cvt_pk_fp8_f32(fl[0], fl[1], 0, 0);
      w0     = __builtin_amdgcn_cvt_pk_fp8_f32(fl[2], fl[3], w0, 1);
      int w1 = __builtin_amdgcn_cvt_pk_fp8_f32(fl[4], fl[5], 0, 0);
      w1     = __builtin_amdgcn_cvt_pk_fp8_f32(fl[6], fl[7], w1, 1);
      int w2 = __builtin_amdgcn_cvt_pk_fp8_f32(fh[0], fh[1], 0, 0);
      w2     = __builtin_amdgcn_cvt_pk_fp8_f32(fh[2], fh[3], w2, 1);
      int w3 = __builtin_amdgcn_cvt_pk_fp8_f32(fh[4], fh[5], 0, 0);
      w3     = __builtin_amdgcn_cvt_pk_fp8_f32(fh[6], fh[7], w3, 1);
      uchar_t* dst = (ot < 4) ? Qf8 : Kf8;
      const size_t chunk = (size_t)((px0>>5) + g)*8 + (ot&3)*2 + e;
      int4 pk4; pk4.x = w0; pk4.y = w1; pk4.z = w2; pk4.w = w3;
      *(int4*)(dst + (chunk<<10) + lane*16) = pk4;
    } else {
      const int ocv0 = (ot-8)*64 + ocl;
      float* vb = V + (((size_t)(src*8 + b)*128) << 10) + hw0;
      #pragma unroll
      for (int lg = 0; lg < 4; lg++) {
        vb[(size_t)(ocv0+0)*1024 + lg*16 + mrow] = acc[lg][0] + bias4.x;
        vb[(size_t)(ocv0+1)*1024 + lg*16 + mrow] = acc[lg][1] + bias4.y;
        vb[(size_t)(ocv0+2)*1024 + lg*16 + mrow] = acc[lg][2] + bias4.z;
        vb[(size_t)(ocv0+3)*1024 + lg*16 + mrow] = acc[lg][3] + bias4.w;
      }
    }
  }
}

// ---------------------------------------------------------------------------
// K3: MX-scaled fp8 MFMA 32x32x64 (unit scales = plain fp8 at 2x rate).
//   Block = 512 rows x one key-batch (1024 cols), 8 waves x 64 rows (2 rg32),
//   2 waves/SIMD, LDS double-buffered 2x32KB, __syncthreads stage loop,
//   stage loop ROLLED (R3: full unroll -> 50MB spill).
//   R8: asm-pinned ds_read pipeline, counted lgkmcnt(8) + sched_barrier(0).
//   R9: + s_setprio(1) around each pinned burst (62.5us, MfmaUtil 46%).
//   Parked: 7 structural attempts (occupancy, pipelining, direct-L2,
//   8-phase, setprio) all land 62-90us; 46% of the 29us MX ceiling.
//   Pm layout: [batch(16)][row(16384)].  Grid 512 x 512 threads.
// ---------------------------------------------------------------------------
#define RD8A(FR, CGL)                                                       \
  _Pragma("unroll")                                                         \
  for (int t = 0; t < 8; t++)                                               \
    asm volatile("ds_read_b128 %0, %1 offset:%c2"                           \
                 : "=v"(FR[t]) : "v"(kb), "i"((CGL)*8192 + t*1024));

#define WAITK(N)                                                            \
  asm volatile("s_waitcnt lgkmcnt(" #N ")" ::: "memory");                   \
  __builtin_amdgcn_sched_barrier(0);

#define QK_BURST(FR)                                                        \
  {                                                                         \
    f32x16 a0 = zv, a1 = zv;                                                \
    __builtin_amdgcn_s_setprio(1);                                          \
    _Pragma("unroll")                                                       \
    for (int u = 0; u < 4; u++) {                                           \
      const v8i bu = (v8i){FR[2*u][0],   FR[2*u][1],   FR[2*u][2],   FR[2*u][3], \
                           FR[2*u+1][0], FR[2*u+1][1], FR[2*u+1][2], FR[2*u+1][3]}; \
      a0 = __builtin_amdgcn_mfma_scale_f32_32x32x64_f8f6f4(                 \
          qa[0][u], bu, a0, 0, 0, 0, 0x7F7F7F7F, 0, 0x7F7F7F7F);            \
      a1 = __builtin_amdgcn_mfma_scale_f32_32x32x64_f8f6f4(                 \
          qa[1][u], bu, a1, 0, 0, 0, 0x7F7F7F7F, 0, 0x7F7F7F7F);            \
    }                                                                       \
    __builtin_amdgcn_s_setprio(0);                                          \
    _Pragma("unroll")                                                       \
    for (int i = 0; i < 16; i++) {                                          \
      rmax[0][i] = fmaxf(rmax[0][i], a0[i]);                                \
      rmax[1][i] = fmaxf(rmax[1][i], a1[i]);                                \
    }                                                                       \
  }

__global__ __launch_bounds__(512, 2) void k3_smax(
    const uchar_t* __restrict__ Qf8, const uchar_t* __restrict__ Kf8,
    float* __restrict__ Pm)
{
  __shared__ __align__(16) uchar_t Kl[2][32768];   // 2 x 32 KB

  const int tid = threadIdx.x;
  const int bt = blockIdx.x >> 5;      // key-batch 0..15
  const int rt = blockIdx.x & 31;      // row-tile (512 rows)
  const int w = tid >> 6, lane = tid & 63;   // w: 0..7
  const int ln31 = lane & 31, half = lane >> 5;

  const int rgb = rt*16 + w*2;         // wave's first row-grp32 (owns 2)
  const int ph = (blockIdx.x & 1)*4;   // stage-phase rotation (8 stages)

  // prologue: stage s=0: 32 chunks (4 cgl x 8 kp); wave w -> c = w*4..w*4+3
  #pragma unroll
  for (int q = 0; q < 4; q++) {
    const int c = w*4 + q;             // cgl = c>>3, kp = c&7
    const int cg = bt*32 + ph*4 + (c>>3);
    gl_lds16(Kf8 + (((size_t)cg*8 + (c&7))<<10) + lane*16, &Kl[0][c*1024]);
  }

  // Q fragments: 2 rg x 4 u-windows, v8i each (64 VGPR), resident whole kernel
  v8i qa[2][4];
  #pragma unroll
  for (int rg = 0; rg < 2; rg++)
    #pragma unroll
    for (int u = 0; u < 4; u++) {
      const int4 p0 = *(const int4*)(Qf8 + (((size_t)(rgb + rg)*8 + 2*u+0)<<10) + lane*16);
      const int4 p1 = *(const int4*)(Qf8 + (((size_t)(rgb + rg)*8 + 2*u+1)<<10) + lane*16);
      qa[rg][u] = (v8i){p0.x, p0.y, p0.z, p0.w, p1.x, p1.y, p1.z, p1.w};
    }

  f32x16 zv;
  #pragma unroll
  for (int i = 0; i < 16; i++) zv[i] = 0.f;
  f32x16 rmax[2];
  #pragma unroll
  for (int rg = 0; rg < 2; rg++)
    #pragma unroll
    for (int i = 0; i < 16; i++) rmax[rg][i] = -3.4e38f;

  const unsigned kb0 = lds_addr(&Kl[0][0]) + lane*16;
  const unsigned kb1 = lds_addr(&Kl[1][0]) + lane*16;

  #pragma unroll 1                      // KEEP ROLLED (R3: unroll -> spill)
  for (int s = 0; s < 8; s++) {
    __syncthreads();                   // stage s data visible; vmcnt drained
    if (s < 7) {
      const int sn = (s + 1 + ph) & 7;
      #pragma unroll
      for (int q = 0; q < 4; q++) {
        const int c = w*4 + q;
        const int cg = bt*32 + sn*4 + (c>>3);
        gl_lds16(Kf8 + (((size_t)cg*8 + (c&7))<<10) + lane*16,
                 &Kl[(s+1)&1][c*1024]);
      }
    }
    const unsigned kb = (s & 1) ? kb1 : kb0;

    v4i fA[8], fB[8];
    RD8A(fA, 0)                        // 8 outstanding
    RD8A(fB, 1)                        // 16 outstanding
    WAITK(8)                           // fA ready, fB in flight
    QK_BURST(fA)                       // cgl 0
    RD8A(fA, 2)                        // 16 outstanding (fB + fA')
    WAITK(8)                           // fB ready, fA' in flight
    QK_BURST(fB)                       // cgl 1
    RD8A(fB, 3)                        // 16 outstanding (fA' + fB')
    WAITK(8)                           // fA' ready, fB' in flight
    QK_BURST(fA)                       // cgl 2
    WAITK(0)                           // fB' ready; clean counter for barrier
    QK_BURST(fB)                       // cgl 3
  }

  // epilogue: per-row max over 32 cols (5 xor-shuffles in each 32-lane half)
  // C/D: col = lane&31, row = (reg&3) + 8*(reg>>2) + 4*half (shape-determined)
  #pragma unroll
  for (int rg = 0; rg < 2; rg++) {
    #pragma unroll
    for (int e = 0; e < 16; e++) {
      float v = rmax[rg][e];
      v = fmaxf(v, __shfl_xor(v, 1));
      v = fmaxf(v, __shfl_xor(v, 2));
      v = fmaxf(v, __shfl_xor(v, 4));
      v = fmaxf(v, __shfl_xor(v, 8));
      v = fmaxf(v, __shfl_xor(v, 16));
      if (ln31 == 0) {
        const int row = rt*512 + w*64 + rg*32 + (e&3) + 8*(e>>2) + 4*half;
        Pm[(size_t)bt*16384 + row] = v;
      }
    }
  }
}

// ---------------------------------------------------------------------------
// K4: the 32 distinct gate softmaxes, computed ONCE each.
//   Grid 32 = (b 8) x (gidx 4); SW[gidx][b][hw] = softmax weight row.
// ---------------------------------------------------------------------------
__global__ __launch_bounds__(256) void k4_smweights(
    const float* __restrict__ Pm, float* __restrict__ SW)
{
  __shared__ float xw[2][4];
  const int tid = threadIdx.x;
  const int b = blockIdx.x >> 2, gidx = blockIdx.x & 3;
  const int qset = gidx >> 1, side = gidx & 1;

  // logits for hw = tid*4 .. tid*4+3 (coalesced float4 per batch)
  const float4* Pm4 = (const float4*)(Pm + (size_t)side*8*16384 + qset*8192 + b*1024);
  float4 l = {0.f, 0.f, 0.f, 0.f};
  #pragma unroll
  for (int t = 0; t < 8; t++) {
    const float4 p = Pm4[t*4096 + tid];
    l.x += p.x; l.y += p.y; l.z += p.z; l.w += p.w;
  }
  const float sc = 0.125f * 0.0625f;   // mean over 8 batches * 1/sqrt(256)
  l.x *= sc; l.y *= sc; l.z *= sc; l.w *= sc;

  const int w = tid >> 6, lane = tid & 63;
  float m = fmaxf(fmaxf(l.x, l.y), fmaxf(l.z, l.w));
  #pragma unroll
  for (int d = 1; d < 64; d <<= 1) m = fmaxf(m, __shfl_xor(m, d));
  if (lane == 0) xw[0][w] = m;
  __syncthreads();
  m = fmaxf(fmaxf(xw[0][0], xw[0][1]), fmaxf(xw[0][2], xw[0][3]));

  float4 e;
  e.x = expf(l.x - m); e.y = expf(l.y - m);
  e.z = expf(l.z - m); e.w = expf(l.w - m);
  float s = e.x + e.y + e.z + e.w;
  #pragma unroll
  for (int d = 1; d < 64; d <<= 1) s += __shfl_xor(s, d);
  if (lane == 0) xw[1][w] = s;
  __syncthreads();
  s = xw[1][0] + xw[1][1] + xw[1][2] + xw[1][3];
  const float inv = 1.f / s;

  float4 r;
  r.x = e.x*inv; r.y = e.y*inv; r.z = e.z*inv; r.w = e.w*inv;
  *(float4*)&SW[((size_t)(gidx*8 + b) << 10) + (tid << 2)] = r;
}

// ---------------------------------------------------------------------------
// K5: pure streaming gate apply: out[b][ch][hw] = SW[gidx][b][hw] * V + b128.
//   Block = one (b, ch) pair, 256 threads x 1 float4.  Fully coalesced.
//   ch: [x34|a_x4|x43|b_x3]
// ---------------------------------------------------------------------------
__global__ __launch_bounds__(256) void k5_out(
    const float* __restrict__ V, const float* __restrict__ SW,
    const float* __restrict__ b128, float* __restrict__ out)
{
  const int tid = threadIdx.x;
  const int ch = blockIdx.x & 511, b = blockIdx.x >> 9;
  const int blk = ch >> 7, o = ch & 127;
  const int gidx = (blk == 0) ? 2 : (blk == 1) ? 0 : (blk == 2) ? 1 : 3;
  const int src = (blk >= 2) ? 1 : 0;

  const int hw0 = tid << 2;
  const float4 sw = *(const float4*)&SW[((size_t)(gidx*8 + b) << 10) + hw0];
  const float4 v = *(const float4*)&V[((size_t)((src*8 + b)*128 + o) << 10) + hw0];
  const float bias = b128[o];
  float4 r;
  r.x = sw.x*v.x + bias; r.y = sw.y*v.y + bias;
  r.z = sw.z*v.z + bias; r.w = sw.w*v.w + bias;
  *(float4*)&out[((size_t)(b*512 + ch) << 10) + hw0] = r;
}

// ---------------------------------------------------------------------------
extern "C" void kernel_launch(void* const* d_in, const int* in_sizes, int n_in,
                              void* d_out, int out_size, void* d_ws, size_t ws_size,
                              hipStream_t stream)
{
  const float* x4   = (const float*)d_in[0];
  const float* x3   = (const float*)d_in[1];
  const float* wq   = (const float*)d_in[2];
  const float* bq   = (const float*)d_in[3];
  const float* wk   = (const float*)d_in[4];
  const float* bk   = (const float*)d_in[5];
  const float* wv   = (const float*)d_in[6];
  const float* bv   = (const float*)d_in[7];
  const float* w128 = (const float*)d_in[8];
  const float* b128 = (const float*)d_in[9];
  float* out = (float*)d_out;

  char* ws = (char*)d_ws;
  uchar_t*  Qf8 = (uchar_t*)ws;  ws += (size_t)512*8*1024;      // 4 MB
  uchar_t*  Kf8 = (uchar_t*)ws;  ws += (size_t)512*8*1024;      // 4 MB
  float*    V   = (float*)ws;    ws += (size_t)2*8*128*1024*4;  // 8 MB
  float*    Pm  = (float*)ws;    ws += (size_t)16*16384*4;      // 1 MB
  ushort_t* Wf  = (ushort_t*)ws; ws += (size_t)640*256*2;       // 320 KB
  float* bias_all = (float*)ws;  ws += (size_t)640*4;           // 2.5 KB
  float* SW = (float*)ws;                                       // 128 KB

  k1_weights  <<<640,  256, 0, stream>>>(wq, bq, wk, bk, wv, bv, w128, Wf, bias_all);
  k2_features <<<256,  256, 0, stream>>>(x4, x3, Wf, bias_all, Qf8, Kf8, V);
  k3_smax     <<<512,  512, 0, stream>>>(Qf8, Kf8, Pm);
  k4_smweights<<<32,   256, 0, stream>>>(Pm, SW);
  k5_out      <<<4096, 256, 0, stream>>>(V, SW, b128, out);
}